// Round 1
// baseline (418.185 us; speedup 1.0000x reference)
//
#include <hip/hip_runtime.h>
#include <math.h>

#define DIM  1024
#define HID  512
#define SHID 1024
#define NTOK 4096
#define NE   8
#define NROW 8192   // NTOK * TOPK

typedef __attribute__((ext_vector_type(8))) short  bfx8;   // 8 bf16 (4 VGPRs)
typedef __attribute__((ext_vector_type(8))) unsigned short u16x8;
typedef __attribute__((ext_vector_type(4))) float  fx4;

__device__ __forceinline__ unsigned short f2bf(float f){
  unsigned int u = __float_as_uint(f);
  unsigned int r = (u + 0x7FFFu + ((u >> 16) & 1u)) >> 16;
  return (unsigned short)r;
}

// ---------------- zero scratch counters ----------------
__global__ void zero_k(int* counts, int* bcount){
  int t = threadIdx.x;
  if (t < NE) counts[t] = 0;
  if (t < 64) bcount[t] = 0;
}

// ---------------- f32 -> bf16 convert ----------------
__global__ __launch_bounds__(256) void cvt_k(const float* __restrict__ s,
                                             unsigned short* __restrict__ d, int n4){
  int i = blockIdx.x*256 + threadIdx.x;
  if (i < n4){
    float4 v = ((const float4*)s)[i];
    ushort4 o;
    o.x = f2bf(v.x); o.y = f2bf(v.y); o.z = f2bf(v.z); o.w = f2bf(v.w);
    ((ushort4*)d)[i] = o;
  }
}

// ---------------- gate: logits, softmax, group-limited top-2 ----------------
__global__ __launch_bounds__(64) void gate_k(const float* __restrict__ x,
    const float* __restrict__ wg, const float* __restrict__ bias,
    int* __restrict__ topk, float* __restrict__ wts, int* __restrict__ counts)
{
  int t = blockIdx.x;
  int l = threadIdx.x;
  const float4* xr = (const float4*)(x + (size_t)t*DIM);
  float acc[NE];
  #pragma unroll
  for (int e=0;e<NE;e++) acc[e]=0.f;
  #pragma unroll
  for (int it=0; it<4; ++it){
    int idx = l + it*64;
    float4 xv = xr[idx];
    #pragma unroll
    for (int e=0;e<NE;e++){
      float4 wv = ((const float4*)(wg + (size_t)e*DIM))[idx];
      acc[e] += xv.x*wv.x + xv.y*wv.y + xv.z*wv.z + xv.w*wv.w;
    }
  }
  #pragma unroll
  for (int off=32; off>=1; off>>=1){
    #pragma unroll
    for (int e=0;e<NE;e++) acc[e] += __shfl_xor(acc[e], off, 64);
  }
  if (l==0){
    float m = acc[0];
    for (int e=1;e<NE;e++) m = fmaxf(m, acc[e]);
    float p[NE], s=0.f;
    for (int e=0;e<NE;e++){ p[e]=expf(acc[e]-m); s+=p[e]; }
    float inv = 1.f/s;
    float sc[NE], sb[NE];
    for (int e=0;e<NE;e++){ sc[e]=p[e]*inv; sb[e]=sc[e]+bias[e]; }
    float gs[4];
    for (int g=0; g<4; g++) gs[g] = sb[2*g] + sb[2*g+1];   // top-2 of 2 == sum
    int g1=0;
    for (int g=1; g<4; g++) if (gs[g] > gs[g1]) g1=g;       // ties -> lower idx
    int g2=-1;
    for (int g=0; g<4; g++){ if (g==g1) continue; if (g2<0 || gs[g]>gs[g2]) g2=g; }
    int e1=-1, e2=-1;
    for (int e=0;e<NE;e++){
      int g=e>>1; if (g!=g1 && g!=g2) continue;
      if (e1<0 || sb[e]>sb[e1]) e1=e;
    }
    for (int e=0;e<NE;e++){
      int g=e>>1; if (g!=g1 && g!=g2) continue;
      if (e==e1) continue;
      if (e2<0 || sb[e]>sb[e2]) e2=e;
    }
    topk[2*t]   = e1;  topk[2*t+1] = e2;
    wts[2*t]    = sc[e1];  wts[2*t+1] = sc[e2];
    atomicAdd(&counts[e1],1); atomicAdd(&counts[e2],1);
  }
}

__global__ void offs_k(const int* counts, int* offs){
  if (threadIdx.x==0 && blockIdx.x==0){
    int s=0;
    for (int e=0;e<NE;e++){ s += counts[e]; offs[e]=s; }   // inclusive cumsum
  }
}

// ---------------- bf16 MFMA GEMM: C[m][n] = sum_k A[m][k]*B[n][k] ----------------
// 128x128 tile, BK=32, 4 waves (2x2), 4x4 fragments of 16x16x32 per wave.
// EPI: 0 -> Cf=f32 out; 1 -> h=silu(AUX)*C, bf16 to Hb; 2 -> Cf=f32 out (d_out)
template<int EPI>
__global__ __launch_bounds__(256) void gemm_bt(
    const unsigned short* __restrict__ A,
    const unsigned short* __restrict__ B,
    const float* __restrict__ AUX,
    float* __restrict__ Cf,
    unsigned short* __restrict__ Hb,
    int M, int N, int K)
{
  __shared__ unsigned short As[128*32];
  __shared__ unsigned short Bs[128*32];
  const int tid  = threadIdx.x;
  const int lane = tid & 63;
  const int wave = tid >> 6;
  const int nbn  = N >> 7;
  const int bm   = blockIdx.x / nbn;
  const int bn   = blockIdx.x % nbn;
  const size_t m0 = (size_t)bm * 128;
  const size_t n0 = (size_t)bn * 128;
  const int wr = wave >> 1, wc = wave & 1;

  fx4 zero = {0.f,0.f,0.f,0.f};
  fx4 acc[4][4];
  #pragma unroll
  for (int i=0;i<4;i++)
    #pragma unroll
    for (int j=0;j<4;j++) acc[i][j] = zero;

  const int c0 = tid, c1 = tid + 256;     // 512 chunks of 8 bf16 cover 128x32
  const int r0 = c0 >> 2, kc0 = c0 & 3;
  const int r1 = c1 >> 2, kc1 = c1 & 3;
  const unsigned short* Ab = A + m0*(size_t)K;
  const unsigned short* Bb = B + n0*(size_t)K;
  const int fr = lane & 15;
  const int fk = (lane >> 4) * 8;

  for (int k0=0; k0<K; k0+=32){
    u16x8 av0 = *(const u16x8*)(Ab + (size_t)r0*K + k0 + kc0*8);
    u16x8 av1 = *(const u16x8*)(Ab + (size_t)r1*K + k0 + kc1*8);
    u16x8 bv0 = *(const u16x8*)(Bb + (size_t)r0*K + k0 + kc0*8);
    u16x8 bv1 = *(const u16x8*)(Bb + (size_t)r1*K + k0 + kc1*8);
    __syncthreads();
    *(u16x8*)&As[c0*8] = av0;
    *(u16x8*)&As[c1*8] = av1;
    *(u16x8*)&Bs[c0*8] = bv0;
    *(u16x8*)&Bs[c1*8] = bv1;
    __syncthreads();
    bfx8 af[4], bfv[4];
    #pragma unroll
    for (int m=0;m<4;m++) af[m]  = *(const bfx8*)&As[(wr*64 + m*16 + fr)*32 + fk];
    #pragma unroll
    for (int n=0;n<4;n++) bfv[n] = *(const bfx8*)&Bs[(wc*64 + n*16 + fr)*32 + fk];
    #pragma unroll
    for (int m=0;m<4;m++)
      #pragma unroll
      for (int n=0;n<4;n++)
        acc[m][n] = __builtin_amdgcn_mfma_f32_16x16x32_bf16(af[m], bfv[n], acc[m][n], 0, 0, 0);
  }

  const int rs = (lane >> 4) * 4;   // C/D: row=(l>>4)*4+r, col=l&15  [m89]
  #pragma unroll
  for (int m=0;m<4;m++){
    #pragma unroll
    for (int n=0;n<4;n++){
      #pragma unroll
      for (int r=0;r<4;r++){
        size_t row = m0 + wr*64 + m*16 + rs + r;
        size_t col = n0 + wc*64 + n*16 + fr;
        size_t idx = row*(size_t)N + col;
        float v = acc[m][n][r];
        if (EPI==1){
          float a = AUX[idx];
          float h = (a / (1.f + expf(-a))) * v;   // silu(C1)*C3
          Hb[idx] = f2bf(h);
        } else {
          Cf[idx] = v;
        }
      }
    }
  }
}

// ---------------- P-GEMVs: P1[f][e][j]=x[f]@w1[e][:,j], P3 same for w3 ----------------
// grid: 128 blocks = e(8) x jc(16, 32 cols each); threads 256 = 32 j x 8 k-parts
__global__ __launch_bounds__(256) void pgemv_k(const float* __restrict__ x,
    const float* __restrict__ w1, const float* __restrict__ w3,
    float* __restrict__ P1, float* __restrict__ P3)
{
  __shared__ float xs[8*DIM];          // tokens 0..7 = first 8192 floats of x
  __shared__ float red[8][32][16];
  int e  = blockIdx.x >> 4;
  int jc = blockIdx.x & 15;
  int t  = threadIdx.x;
  for (int q=t; q<2048; q+=256) ((float4*)xs)[q] = ((const float4*)x)[q];
  __syncthreads();
  int j  = jc*32 + (t & 31);
  int kp = t >> 5;                      // 0..7, 128 k each
  float a1[8], a3[8];
  #pragma unroll
  for (int f=0;f<8;f++){ a1[f]=0.f; a3[f]=0.f; }
  const float* w1p = w1 + (size_t)e*DIM*HID + j;
  const float* w3p = w3 + (size_t)e*DIM*HID + j;
  #pragma unroll 4
  for (int k=kp*128; k<kp*128+128; ++k){
    float w1v = w1p[(size_t)k*HID];
    float w3v = w3p[(size_t)k*HID];
    #pragma unroll
    for (int f=0;f<8;f++){
      float xv = xs[f*DIM + k];
      a1[f] += xv*w1v;
      a3[f] += xv*w3v;
    }
  }
  #pragma unroll
  for (int f=0;f<8;f++){ red[kp][t&31][f] = a1[f]; red[kp][t&31][8+f] = a3[f]; }
  __syncthreads();
  if (kp==0){
    #pragma unroll
    for (int f=0;f<8;f++){
      float s1=0.f, s3=0.f;
      #pragma unroll
      for (int q=0;q<8;q++){ s1 += red[q][t][f]; s3 += red[q][t][8+f]; }
      P1[((size_t)f*8 + e)*HID + j] = s1;
      P3[((size_t)f*8 + e)*HID + j] = s3;
    }
  }
}

// ---------------- scatter rows into (f, eid) buckets ----------------
__global__ __launch_bounds__(256) void scat_k(const int* __restrict__ topk,
    const float* __restrict__ wts, const int* __restrict__ offs,
    int* __restrict__ bcount, float* __restrict__ bw)
{
  int i = blockIdx.x*256 + threadIdx.x;
  if (i >= NROW) return;
  int f = topk[i];
  int e = 0;
  #pragma unroll
  for (int q=0;q<8;q++) if (i >= offs[q]) e = q+1;  // searchsorted right
  float w = wts[i];
  int b = f*8 + e;
  int slot = atomicAdd(&bcount[b], 1);
  bw[(size_t)b*NROW + slot] = w;
}

// ---------------- per-bucket silu-weighted sums: H[r][e][j] ----------------
__global__ __launch_bounds__(256) void bsum_k(const float* __restrict__ P1,
    const float* __restrict__ P3, const int* __restrict__ bcount,
    const float* __restrict__ bw, float* __restrict__ H)
{
  int b = blockIdx.x;        // r*8+e
  int t = threadIdx.x;
  int n = bcount[b];
  float a0 = P1[(size_t)b*HID + t];
  float a1 = P1[(size_t)b*HID + t + 256];
  float s0 = 0.f, s1 = 0.f;
  const float* wp = bw + (size_t)b*NROW;
  for (int q=0;q<n;q++){
    float w = wp[q];
    float z0 = w*a0, z1 = w*a1;
    s0 += w * z0 / (1.f + expf(-z0));   // w * silu(w*a)
    s1 += w * z1 / (1.f + expf(-z1));
  }
  H[(size_t)b*HID + t]       = P3[(size_t)b*HID + t]       * s0;
  H[(size_t)b*HID + t + 256] = P3[(size_t)b*HID + t + 256] * s1;
}

// ---------------- routed out: out[r][d] += sum_e H[r][e] @ w2[e][:,d] ----------------
// grid: 128 blocks = e(8) x dc(16, 64 cols each); threads 256 = 64 d x 4 j-parts
__global__ __launch_bounds__(256) void rout_k(const float* __restrict__ H,
    const float* __restrict__ w2, float* __restrict__ out)
{
  __shared__ float Hs[8*HID];          // 16KB
  __shared__ float red[4][64][8];      // 8KB
  int e  = blockIdx.x >> 4;
  int dc = blockIdx.x & 15;
  int t  = threadIdx.x;
  for (int q=t; q<8*HID; q+=256){
    int r = q >> 9; int j = q & 511;
    Hs[q] = H[((size_t)r*8 + e)*HID + j];
  }
  __syncthreads();
  int d  = dc*64 + (t & 63);
  int jp = t >> 6;                      // 0..3, 128 j each
  float acc[8];
  #pragma unroll
  for (int r=0;r<8;r++) acc[r]=0.f;
  const float* w2p = w2 + (size_t)e*HID*DIM + d;
  #pragma unroll 4
  for (int j=jp*128; j<jp*128+128; ++j){
    float wv = w2p[(size_t)j*DIM];
    #pragma unroll
    for (int r=0;r<8;r++) acc[r] += Hs[r*HID + j]*wv;
  }
  #pragma unroll
  for (int r=0;r<8;r++) red[jp][t&63][r] = acc[r];
  __syncthreads();
  if (jp==0){
    #pragma unroll
    for (int r=0;r<8;r++){
      float v = red[0][t][r] + red[1][t][r] + red[2][t][r] + red[3][t][r];
      atomicAdd(&out[(size_t)r*DIM + d], v);
    }
  }
}

extern "C" void kernel_launch(void* const* d_in, const int* in_sizes, int n_in,
                              void* d_out, int out_size, void* d_ws, size_t ws_size,
                              hipStream_t stream)
{
  const float* x    = (const float*)d_in[0];
  const float* wg   = (const float*)d_in[1];
  const float* w1   = (const float*)d_in[2];
  const float* w2   = (const float*)d_in[3];   // NOTE: w2 before w3 in dict order
  const float* w3   = (const float*)d_in[4];
  const float* sw1  = (const float*)d_in[5];
  const float* sw2  = (const float*)d_in[6];   // sw2 before sw3
  const float* sw3  = (const float*)d_in[7];
  const float* bias = (const float*)d_in[8];
  float* out = (float*)d_out;

  char* wsp = (char*)d_ws;
  size_t off = 0;
  auto alloc = [&](size_t bytes)->char*{
    char* p = wsp + off; off += (bytes + 255) & ~(size_t)255; return p;
  };
  unsigned short* xb   = (unsigned short*)alloc((size_t)NTOK*DIM*2);
  unsigned short* s1b  = (unsigned short*)alloc((size_t)SHID*DIM*2);
  unsigned short* s3b  = (unsigned short*)alloc((size_t)SHID*DIM*2);
  unsigned short* s2b  = (unsigned short*)alloc((size_t)DIM*SHID*2);
  float*          C1   = (float*)alloc((size_t)NTOK*SHID*4);
  unsigned short* hb   = (unsigned short*)alloc((size_t)NTOK*SHID*2);
  int*            topk = (int*)alloc(NROW*4);
  float*          wtsb = (float*)alloc(NROW*4);
  int*            cnts = (int*)alloc(64);
  int*            offs = (int*)alloc(64);
  int*            bcnt = (int*)alloc(256);
  float*          P1   = (float*)alloc(64*HID*4);
  float*          P3   = (float*)alloc(64*HID*4);
  float*          Hbuf = (float*)alloc(64*HID*4);
  float*          bwb  = (float*)alloc((size_t)64*NROW*4);
  (void)ws_size; (void)in_sizes; (void)n_in; (void)out_size;

  zero_k<<<1, 64, 0, stream>>>(cnts, bcnt);
  cvt_k<<<(NTOK*DIM/4)/256, 256, 0, stream>>>(x,   xb,  NTOK*DIM/4);
  cvt_k<<<(SHID*DIM/4)/256, 256, 0, stream>>>(sw1, s1b, SHID*DIM/4);
  cvt_k<<<(SHID*DIM/4)/256, 256, 0, stream>>>(sw3, s3b, SHID*DIM/4);
  cvt_k<<<(DIM*SHID/4)/256, 256, 0, stream>>>(sw2, s2b, DIM*SHID/4);
  gate_k<<<NTOK, 64, 0, stream>>>(x, wg, bias, topk, wtsb, cnts);
  offs_k<<<1, 1, 0, stream>>>(cnts, offs);

  gemm_bt<0><<<(NTOK/128)*(SHID/128), 256, 0, stream>>>(xb, s1b, nullptr, C1, nullptr, NTOK, SHID, DIM);
  gemm_bt<1><<<(NTOK/128)*(SHID/128), 256, 0, stream>>>(xb, s3b, C1, nullptr, hb, NTOK, SHID, DIM);
  gemm_bt<2><<<(NTOK/128)*(DIM/128),  256, 0, stream>>>(hb, s2b, nullptr, out, nullptr, NTOK, DIM, SHID);

  pgemv_k<<<128, 256, 0, stream>>>(x, w1, w3, P1, P3);
  scat_k<<<NROW/256, 256, 0, stream>>>(topk, wtsb, offs, bcnt, bwb);
  bsum_k<<<64, 256, 0, stream>>>(P1, P3, bcnt, bwb, Hbuf);
  rout_k<<<128, 256, 0, stream>>>(Hbuf, w2, out);
}

// Round 3
// 317.378 us; speedup vs baseline: 1.3176x; 1.3176x over previous
//
#include <hip/hip_runtime.h>
#include <math.h>

#define DIM  1024
#define HID  512
#define SHID 1024
#define NTOK 4096
#define NE   8
#define NROW 8192   // NTOK * TOPK

typedef __attribute__((ext_vector_type(8))) short  bfx8;   // 8 bf16 (4 VGPRs)
typedef __attribute__((ext_vector_type(8))) unsigned short u16x8;
typedef __attribute__((ext_vector_type(4))) float  fx4;

__device__ __forceinline__ unsigned short f2bf(float f){
  unsigned int u = __float_as_uint(f);
  unsigned int r = (u + 0x7FFFu + ((u >> 16) & 1u)) >> 16;
  return (unsigned short)r;
}

#define GLOAD16(g, l) __builtin_amdgcn_global_load_lds( \
    (const __attribute__((address_space(1))) unsigned int*)(g), \
    (__attribute__((address_space(3))) unsigned int*)(l), 16, 0, 0)

// ---------------- zero scratch counters ----------------
__global__ void zero_k(int* counts, int* bcount){
  int t = threadIdx.x;
  if (t < NE) counts[t] = 0;
  if (t < 64) bcount[t] = 0;
}

// ---------------- f32 -> bf16 convert ----------------
__global__ __launch_bounds__(256) void cvt_k(const float* __restrict__ s,
                                             unsigned short* __restrict__ d, int n4){
  int i = blockIdx.x*256 + threadIdx.x;
  if (i < n4){
    float4 v = ((const float4*)s)[i];
    ushort4 o;
    o.x = f2bf(v.x); o.y = f2bf(v.y); o.z = f2bf(v.z); o.w = f2bf(v.w);
    ((ushort4*)d)[i] = o;
  }
}

// ---------------- logits: wave per token, no atomics, no serial tail ----------------
__global__ __launch_bounds__(256) void logits_k(const float* __restrict__ x,
    const float* __restrict__ wg, float* __restrict__ logits)
{
  int w = threadIdx.x >> 6, l = threadIdx.x & 63;
  int t = blockIdx.x*4 + w;
  const float4* xr = (const float4*)(x + (size_t)t*DIM);
  float acc[NE];
  #pragma unroll
  for (int e=0;e<NE;e++) acc[e]=0.f;
  #pragma unroll
  for (int it=0; it<4; ++it){
    int idx = l + it*64;
    float4 xv = xr[idx];
    #pragma unroll
    for (int e=0;e<NE;e++){
      float4 wv = ((const float4*)(wg + (size_t)e*DIM))[idx];
      acc[e] += xv.x*wv.x + xv.y*wv.y + xv.z*wv.z + xv.w*wv.w;
    }
  }
  #pragma unroll
  for (int off=32; off>=1; off>>=1){
    #pragma unroll
    for (int e=0;e<NE;e++) acc[e] += __shfl_xor(acc[e], off, 64);
  }
  if (l==0){
    float4 a = {acc[0],acc[1],acc[2],acc[3]};
    float4 b = {acc[4],acc[5],acc[6],acc[7]};
    ((float4*)(logits + (size_t)t*8))[0] = a;
    ((float4*)(logits + (size_t)t*8))[1] = b;
  }
}

// ---------------- top-k: one thread per token; LDS histogram for counts ----------------
__global__ __launch_bounds__(256) void topk_k(const float* __restrict__ logits,
    const float* __restrict__ bias, int* __restrict__ topk,
    float* __restrict__ wts, int* __restrict__ counts)
{
  __shared__ int h[NE];
  int tid = threadIdx.x;
  if (tid < NE) h[tid] = 0;
  __syncthreads();
  int i = blockIdx.x*256 + tid;
  float4 la = ((const float4*)(logits + (size_t)i*8))[0];
  float4 lb = ((const float4*)(logits + (size_t)i*8))[1];
  float lg[NE] = {la.x,la.y,la.z,la.w,lb.x,lb.y,lb.z,lb.w};
  float m = lg[0];
  #pragma unroll
  for (int e=1;e<NE;e++) m = fmaxf(m, lg[e]);
  float p[NE], s=0.f;
  #pragma unroll
  for (int e=0;e<NE;e++){ p[e]=expf(lg[e]-m); s+=p[e]; }
  float inv = 1.f/s;
  float sc[NE], sb[NE];
  #pragma unroll
  for (int e=0;e<NE;e++){ sc[e]=p[e]*inv; sb[e]=sc[e]+bias[e]; }
  float gs[4];
  #pragma unroll
  for (int g=0; g<4; g++) gs[g] = sb[2*g] + sb[2*g+1];   // top-2 of 2 == sum
  int g1=0;
  #pragma unroll
  for (int g=1; g<4; g++) if (gs[g] > gs[g1]) g1=g;      // ties -> lower idx
  int g2=-1;
  #pragma unroll
  for (int g=0; g<4; g++){ if (g==g1) continue; if (g2<0 || gs[g]>gs[g2]) g2=g; }
  int e1=-1, e2=-1;
  #pragma unroll
  for (int e=0;e<NE;e++){
    int g=e>>1; if (g!=g1 && g!=g2) continue;
    if (e1<0 || sb[e]>sb[e1]) e1=e;
  }
  #pragma unroll
  for (int e=0;e<NE;e++){
    int g=e>>1; if (g!=g1 && g!=g2) continue;
    if (e==e1) continue;
    if (e2<0 || sb[e]>sb[e2]) e2=e;
  }
  topk[2*i]   = e1;  topk[2*i+1] = e2;
  wts[2*i]    = sc[e1];  wts[2*i+1] = sc[e2];
  atomicAdd(&h[e1], 1);
  atomicAdd(&h[e2], 1);
  __syncthreads();
  if (tid < NE) atomicAdd(&counts[tid], h[tid]);
}

__global__ void offs_k(const int* counts, int* offs){
  if (threadIdx.x==0 && blockIdx.x==0){
    int s=0;
    for (int e=0;e<NE;e++){ s += counts[e]; offs[e]=s; }   // inclusive cumsum
  }
}

// ---------------- bf16 MFMA GEMM (B^T), global_load_lds staging ----------------
// 128x128 tile, BK=32, 4 waves (2x2), 4x4 frags of 16x16x32 per wave.
// DUAL=1: two B matrices, epilogue Hb = silu(C1)*C3 (bf16). DUAL=0: Cf = C (f32).
template<int DUAL>
__global__ __launch_bounds__(256,1) void gemm_k(
    const unsigned short* __restrict__ A,
    const unsigned short* __restrict__ B1,
    const unsigned short* __restrict__ B3,
    unsigned short* __restrict__ Hb,
    float* __restrict__ Cf,
    int M, int N, int K)
{
  __shared__ unsigned short As [128*32];
  __shared__ unsigned short Bs [128*32];
  __shared__ unsigned short Bs3[DUAL ? 128*32 : 16];
  const int tid  = threadIdx.x;
  const int lane = tid & 63;
  const int wave = tid >> 6;
  const int nbn  = N >> 7;
  const int bm   = blockIdx.x / nbn;
  const int bn   = blockIdx.x % nbn;
  const size_t m0 = (size_t)bm * 128;
  const size_t n0 = (size_t)bn * 128;
  const int wr = wave >> 1, wc = wave & 1;

  fx4 zero = {0.f,0.f,0.f,0.f};
  fx4 acc1[4][4], acc3[4][4];
  #pragma unroll
  for (int i=0;i<4;i++)
    #pragma unroll
    for (int j=0;j<4;j++){ acc1[i][j] = zero; if (DUAL) acc3[i][j] = zero; }

  const int c0 = tid, c1 = tid + 256;     // 512 chunks of 8 bf16 cover 128x32
  const int r0 = c0 >> 2, kc0 = c0 & 3;
  const int r1 = c1 >> 2, kc1 = c1 & 3;
  const unsigned short* Ab = A  + m0*(size_t)K;
  const unsigned short* B1b = B1 + n0*(size_t)K;
  const unsigned short* B3b = DUAL ? (B3 + n0*(size_t)K) : (const unsigned short*)0;
  const int fr = lane & 15;
  const int fk = (lane >> 4) * 8;

  for (int k0=0; k0<K; k0+=32){
    __syncthreads();   // previous compute's LDS reads done before overwrite
    GLOAD16(Ab  + (size_t)r0*K + k0 + kc0*8, &As [c0*8]);
    GLOAD16(Ab  + (size_t)r1*K + k0 + kc1*8, &As [c1*8]);
    GLOAD16(B1b + (size_t)r0*K + k0 + kc0*8, &Bs [c0*8]);
    GLOAD16(B1b + (size_t)r1*K + k0 + kc1*8, &Bs [c1*8]);
    if (DUAL){
      GLOAD16(B3b + (size_t)r0*K + k0 + kc0*8, &Bs3[c0*8]);
      GLOAD16(B3b + (size_t)r1*K + k0 + kc1*8, &Bs3[c1*8]);
    }
    asm volatile("s_waitcnt vmcnt(0)" ::: "memory");
    __syncthreads();
    bfx8 af[4], b1f[4], b3f[4];
    #pragma unroll
    for (int m=0;m<4;m++) af[m]  = *(const bfx8*)&As[(wr*64 + m*16 + fr)*32 + fk];
    #pragma unroll
    for (int n=0;n<4;n++){
      b1f[n] = *(const bfx8*)&Bs[(wc*64 + n*16 + fr)*32 + fk];
      if (DUAL) b3f[n] = *(const bfx8*)&Bs3[(wc*64 + n*16 + fr)*32 + fk];
    }
    #pragma unroll
    for (int m=0;m<4;m++)
      #pragma unroll
      for (int n=0;n<4;n++){
        acc1[m][n] = __builtin_amdgcn_mfma_f32_16x16x32_bf16(af[m], b1f[n], acc1[m][n], 0, 0, 0);
        if (DUAL)
          acc3[m][n] = __builtin_amdgcn_mfma_f32_16x16x32_bf16(af[m], b3f[n], acc3[m][n], 0, 0, 0);
      }
  }

  const int rs = (lane >> 4) * 4;   // C/D: row=(l>>4)*4+r, col=l&15  [m89]
  #pragma unroll
  for (int m=0;m<4;m++){
    #pragma unroll
    for (int n=0;n<4;n++){
      #pragma unroll
      for (int r=0;r<4;r++){
        size_t row = m0 + wr*64 + m*16 + rs + r;
        size_t col = n0 + wc*64 + n*16 + fr;
        size_t idx = row*(size_t)N + col;
        if (DUAL){
          float a = acc1[m][n][r];
          float c = acc3[m][n][r];
          float hsw = (a / (1.f + expf(-a))) * c;   // silu(C1)*C3
          Hb[idx] = f2bf(hsw);
        } else {
          Cf[idx] = acc1[m][n][r];
        }
      }
    }
  }
}

// ---------------- P-GEMVs: P1[f][e][j]=x[f]@w1[e][:,j], P3 same for w3 ----------------
// grid: 128 blocks = e(8) x jc(16, 32 cols each); threads 256 = 32 j x 8 k-parts
__global__ __launch_bounds__(256) void pgemv_k(const float* __restrict__ x,
    const float* __restrict__ w1, const float* __restrict__ w3,
    float* __restrict__ P1, float* __restrict__ P3)
{
  __shared__ float xs[8*DIM];          // tokens 0..7 = first 8192 floats of x
  __shared__ float red[8][32][16];
  int e  = blockIdx.x >> 4;
  int jc = blockIdx.x & 15;
  int t  = threadIdx.x;
  for (int q=t; q<2048; q+=256) ((float4*)xs)[q] = ((const float4*)x)[q];
  __syncthreads();
  int j  = jc*32 + (t & 31);
  int kp = t >> 5;                      // 0..7, 128 k each
  float a1[8], a3[8];
  #pragma unroll
  for (int f=0;f<8;f++){ a1[f]=0.f; a3[f]=0.f; }
  const float* w1p = w1 + (size_t)e*DIM*HID + j;
  const float* w3p = w3 + (size_t)e*DIM*HID + j;
  #pragma unroll 4
  for (int k=kp*128; k<kp*128+128; ++k){
    float w1v = w1p[(size_t)k*HID];
    float w3v = w3p[(size_t)k*HID];
    #pragma unroll
    for (int f=0;f<8;f++){
      float xv = xs[f*DIM + k];
      a1[f] += xv*w1v;
      a3[f] += xv*w3v;
    }
  }
  #pragma unroll
  for (int f=0;f<8;f++){ red[kp][t&31][f] = a1[f]; red[kp][t&31][8+f] = a3[f]; }
  __syncthreads();
  if (kp==0){
    #pragma unroll
    for (int f=0;f<8;f++){
      float s1=0.f, s3=0.f;
      #pragma unroll
      for (int q=0;q<8;q++){ s1 += red[q][t][f]; s3 += red[q][t][8+f]; }
      P1[((size_t)f*8 + e)*HID + j] = s1;
      P3[((size_t)f*8 + e)*HID + j] = s3;
    }
  }
}

// ---------------- scatter rows into (f, eid) buckets ----------------
__global__ __launch_bounds__(256) void scat_k(const int* __restrict__ topk,
    const float* __restrict__ wts, const int* __restrict__ offs,
    int* __restrict__ bcount, float* __restrict__ bw)
{
  int i = blockIdx.x*256 + threadIdx.x;
  if (i >= NROW) return;
  int f = topk[i];
  int e = 0;
  #pragma unroll
  for (int q=0;q<8;q++) if (i >= offs[q]) e = q+1;  // searchsorted right
  float w = wts[i];
  int b = f*8 + e;
  int slot = atomicAdd(&bcount[b], 1);
  bw[(size_t)b*NROW + slot] = w;
}

// ---------------- per-bucket silu-weighted sums: H[r][e][j] ----------------
__global__ __launch_bounds__(256) void bsum_k(const float* __restrict__ P1,
    const float* __restrict__ P3, const int* __restrict__ bcount,
    const float* __restrict__ bw, float* __restrict__ H)
{
  int b = blockIdx.x;        // r*8+e
  int t = threadIdx.x;
  int n = bcount[b];
  float a0 = P1[(size_t)b*HID + t];
  float a1 = P1[(size_t)b*HID + t + 256];
  float s0 = 0.f, s1 = 0.f;
  const float* wp = bw + (size_t)b*NROW;
  for (int q=0;q<n;q++){
    float w = wp[q];
    float z0 = w*a0, z1 = w*a1;
    s0 += w * z0 / (1.f + expf(-z0));   // w * silu(w*a)
    s1 += w * z1 / (1.f + expf(-z1));
  }
  H[(size_t)b*HID + t]       = P3[(size_t)b*HID + t]       * s0;
  H[(size_t)b*HID + t + 256] = P3[(size_t)b*HID + t + 256] * s1;
}

// ---------------- routed out: out[r][d] += sum_e H[r][e] @ w2[e][:,d] ----------------
// grid: 128 blocks = e(8) x dc(16, 64 cols each); threads 256 = 64 d x 4 j-parts
__global__ __launch_bounds__(256) void rout_k(const float* __restrict__ H,
    const float* __restrict__ w2, float* __restrict__ out)
{
  __shared__ float Hs[8*HID];          // 16KB
  __shared__ float red[4][64][8];      // 8KB
  int e  = blockIdx.x >> 4;
  int dc = blockIdx.x & 15;
  int t  = threadIdx.x;
  for (int q=t; q<8*HID; q+=256){
    int r = q >> 9; int j = q & 511;
    Hs[q] = H[((size_t)r*8 + e)*HID + j];
  }
  __syncthreads();
  int d  = dc*64 + (t & 63);
  int jp = t >> 6;                      // 0..3, 128 j each
  float acc[8];
  #pragma unroll
  for (int r=0;r<8;r++) acc[r]=0.f;
  const float* w2p = w2 + (size_t)e*HID*DIM + d;
  #pragma unroll 4
  for (int j=jp*128; j<jp*128+128; ++j){
    float wv = w2p[(size_t)j*DIM];
    #pragma unroll
    for (int r=0;r<8;r++) acc[r] += Hs[r*HID + j]*wv;
  }
  #pragma unroll
  for (int r=0;r<8;r++) red[jp][t&63][r] = acc[r];
  __syncthreads();
  if (jp==0){
    #pragma unroll
    for (int r=0;r<8;r++){
      float v = red[0][t][r] + red[1][t][r] + red[2][t][r] + red[3][t][r];
      atomicAdd(&out[(size_t)r*DIM + d], v);
    }
  }
}

extern "C" void kernel_launch(void* const* d_in, const int* in_sizes, int n_in,
                              void* d_out, int out_size, void* d_ws, size_t ws_size,
                              hipStream_t stream)
{
  const float* x    = (const float*)d_in[0];
  const float* wg   = (const float*)d_in[1];
  const float* w1   = (const float*)d_in[2];
  const float* w2   = (const float*)d_in[3];   // NOTE: w2 before w3 in dict order
  const float* w3   = (const float*)d_in[4];
  const float* sw1  = (const float*)d_in[5];
  const float* sw2  = (const float*)d_in[6];   // sw2 before sw3
  const float* sw3  = (const float*)d_in[7];
  const float* bias = (const float*)d_in[8];
  float* out = (float*)d_out;

  char* wsp = (char*)d_ws;
  size_t off = 0;
  auto alloc = [&](size_t bytes)->char*{
    char* p = wsp + off; off += (bytes + 255) & ~(size_t)255; return p;
  };
  unsigned short* xb   = (unsigned short*)alloc((size_t)NTOK*DIM*2);
  unsigned short* s1b  = (unsigned short*)alloc((size_t)SHID*DIM*2);
  unsigned short* s3b  = (unsigned short*)alloc((size_t)SHID*DIM*2);
  unsigned short* s2b  = (unsigned short*)alloc((size_t)DIM*SHID*2);
  unsigned short* hb   = (unsigned short*)alloc((size_t)NTOK*SHID*2);
  float*          lgt  = (float*)alloc((size_t)NTOK*NE*4);
  int*            topk = (int*)alloc(NROW*4);
  float*          wtsb = (float*)alloc(NROW*4);
  int*            cnts = (int*)alloc(64);
  int*            offs = (int*)alloc(64);
  int*            bcnt = (int*)alloc(256);
  float*          P1   = (float*)alloc(64*HID*4);
  float*          P3   = (float*)alloc(64*HID*4);
  float*          Hbuf = (float*)alloc(64*HID*4);
  float*          bwb  = (float*)alloc((size_t)64*NROW*4);
  (void)ws_size; (void)in_sizes; (void)n_in; (void)out_size;

  zero_k<<<1, 64, 0, stream>>>(cnts, bcnt);
  cvt_k<<<(NTOK*DIM/4)/256, 256, 0, stream>>>(x,   xb,  NTOK*DIM/4);
  cvt_k<<<(SHID*DIM/4)/256, 256, 0, stream>>>(sw1, s1b, SHID*DIM/4);
  cvt_k<<<(SHID*DIM/4)/256, 256, 0, stream>>>(sw3, s3b, SHID*DIM/4);
  cvt_k<<<(DIM*SHID/4)/256, 256, 0, stream>>>(sw2, s2b, DIM*SHID/4);
  logits_k<<<NTOK/4, 256, 0, stream>>>(x, wg, lgt);
  topk_k<<<NTOK/256, 256, 0, stream>>>(lgt, bias, topk, wtsb, cnts);
  offs_k<<<1, 1, 0, stream>>>(cnts, offs);

  // fused shared-expert FFN: hb = silu(x@sw1^T) * (x@sw3^T), then out = hb@sw2^T
  // K of the second GEMM is SHID (=1024) — hb is [NTOK][SHID], sw2 is [DIM][SHID].
  gemm_k<1><<<(NTOK/128)*(SHID/128), 256, 0, stream>>>(xb, s1b, s3b, hb, nullptr, NTOK, SHID, DIM);
  gemm_k<0><<<(NTOK/128)*(DIM/128),  256, 0, stream>>>(hb, s2b, nullptr, nullptr, out, NTOK, DIM, SHID);

  pgemv_k<<<128, 256, 0, stream>>>(x, w1, w3, P1, P3);
  scat_k<<<NROW/256, 256, 0, stream>>>(topk, wtsb, offs, bcnt, bwb);
  bsum_k<<<64, 256, 0, stream>>>(P1, P3, bcnt, bwb, Hbuf);
  rout_k<<<128, 256, 0, stream>>>(Hbuf, w2, out);
}

// Round 4
// 291.276 us; speedup vs baseline: 1.4357x; 1.0896x over previous
//
#include <hip/hip_runtime.h>
#include <math.h>

#define DIM  1024
#define HID  512
#define SHID 1024
#define NTOK 4096
#define NE   8
#define NROW 8192   // NTOK * TOPK

typedef __attribute__((ext_vector_type(8))) short  bfx8;   // 8 bf16 (4 VGPRs)
typedef __attribute__((ext_vector_type(8))) unsigned short u16x8;
typedef __attribute__((ext_vector_type(4))) float  fx4;

__device__ __forceinline__ unsigned short f2bf(float f){
  unsigned int u = __float_as_uint(f);
  unsigned int r = (u + 0x7FFFu + ((u >> 16) & 1u)) >> 16;
  return (unsigned short)r;
}

#define GLOAD16(g, l) __builtin_amdgcn_global_load_lds( \
    (const __attribute__((address_space(1))) unsigned int*)(g), \
    (__attribute__((address_space(3))) unsigned int*)(l), 16, 0, 0)

// ---------------- fused f32 -> bf16 convert for x, sw1, sw3, sw2 ----------------
// segment boundaries are multiples of 256 float4s -> block-uniform branches
__global__ __launch_bounds__(256) void cvtall_k(const float* __restrict__ x,
    const float* __restrict__ sw1, const float* __restrict__ sw3,
    const float* __restrict__ sw2, unsigned short* __restrict__ xb,
    unsigned short* __restrict__ s1b, unsigned short* __restrict__ s3b,
    unsigned short* __restrict__ s2b)
{
  const int NX = (NTOK*DIM)/4;     // 1048576
  const int NW = (SHID*DIM)/4;     // 262144
  int i = blockIdx.x*256 + threadIdx.x;
  const float* s; unsigned short* d; int j;
  if (i < NX)            { s = x;   d = xb;  j = i; }
  else if (i < NX+NW)    { s = sw1; d = s1b; j = i-NX; }
  else if (i < NX+2*NW)  { s = sw3; d = s3b; j = i-NX-NW; }
  else                   { s = sw2; d = s2b; j = i-NX-2*NW; }
  float4 v = ((const float4*)s)[j];
  ushort4 o;
  o.x = f2bf(v.x); o.y = f2bf(v.y); o.z = f2bf(v.z); o.w = f2bf(v.w);
  ((ushort4*)d)[j] = o;
}

// ---------------- logits: wave per token; block 0 zeroes the counters ----------------
__global__ __launch_bounds__(256) void logits_k(const float* __restrict__ x,
    const float* __restrict__ wg, float* __restrict__ logits,
    int* __restrict__ counts, int* __restrict__ bcount)
{
  if (blockIdx.x == 0 && threadIdx.x < 64){
    if (threadIdx.x < NE) counts[threadIdx.x] = 0;
    bcount[threadIdx.x] = 0;
  }
  int w = threadIdx.x >> 6, l = threadIdx.x & 63;
  int t = blockIdx.x*4 + w;
  const float4* xr = (const float4*)(x + (size_t)t*DIM);
  float acc[NE];
  #pragma unroll
  for (int e=0;e<NE;e++) acc[e]=0.f;
  #pragma unroll
  for (int it=0; it<4; ++it){
    int idx = l + it*64;
    float4 xv = xr[idx];
    #pragma unroll
    for (int e=0;e<NE;e++){
      float4 wv = ((const float4*)(wg + (size_t)e*DIM))[idx];
      acc[e] += xv.x*wv.x + xv.y*wv.y + xv.z*wv.z + xv.w*wv.w;
    }
  }
  #pragma unroll
  for (int off=32; off>=1; off>>=1){
    #pragma unroll
    for (int e=0;e<NE;e++) acc[e] += __shfl_xor(acc[e], off, 64);
  }
  if (l==0){
    float4 a = {acc[0],acc[1],acc[2],acc[3]};
    float4 b = {acc[4],acc[5],acc[6],acc[7]};
    ((float4*)(logits + (size_t)t*8))[0] = a;
    ((float4*)(logits + (size_t)t*8))[1] = b;
  }
}

// ---------------- top-k: one thread per token; LDS histogram for counts ----------------
__global__ __launch_bounds__(256) void topk_k(const float* __restrict__ logits,
    const float* __restrict__ bias, int* __restrict__ topk,
    float* __restrict__ wts, int* __restrict__ counts)
{
  __shared__ int h[NE];
  int tid = threadIdx.x;
  if (tid < NE) h[tid] = 0;
  __syncthreads();
  int i = blockIdx.x*256 + tid;
  float4 la = ((const float4*)(logits + (size_t)i*8))[0];
  float4 lb = ((const float4*)(logits + (size_t)i*8))[1];
  float lg[NE] = {la.x,la.y,la.z,la.w,lb.x,lb.y,lb.z,lb.w};
  float m = lg[0];
  #pragma unroll
  for (int e=1;e<NE;e++) m = fmaxf(m, lg[e]);
  float p[NE], s=0.f;
  #pragma unroll
  for (int e=0;e<NE;e++){ p[e]=expf(lg[e]-m); s+=p[e]; }
  float inv = 1.f/s;
  float sc[NE], sb[NE];
  #pragma unroll
  for (int e=0;e<NE;e++){ sc[e]=p[e]*inv; sb[e]=sc[e]+bias[e]; }
  float gs[4];
  #pragma unroll
  for (int g=0; g<4; g++) gs[g] = sb[2*g] + sb[2*g+1];   // top-2 of 2 == sum
  int g1=0;
  #pragma unroll
  for (int g=1; g<4; g++) if (gs[g] > gs[g1]) g1=g;      // ties -> lower idx
  int g2=-1;
  #pragma unroll
  for (int g=0; g<4; g++){ if (g==g1) continue; if (g2<0 || gs[g]>gs[g2]) g2=g; }
  int e1=-1, e2=-1;
  #pragma unroll
  for (int e=0;e<NE;e++){
    int g=e>>1; if (g!=g1 && g!=g2) continue;
    if (e1<0 || sb[e]>sb[e1]) e1=e;
  }
  #pragma unroll
  for (int e=0;e<NE;e++){
    int g=e>>1; if (g!=g1 && g!=g2) continue;
    if (e==e1) continue;
    if (e2<0 || sb[e]>sb[e2]) e2=e;
  }
  topk[2*i]   = e1;  topk[2*i+1] = e2;
  wts[2*i]    = sc[e1];  wts[2*i+1] = sc[e2];
  atomicAdd(&h[e1], 1);
  atomicAdd(&h[e2], 1);
  __syncthreads();
  if (tid < NE) atomicAdd(&counts[tid], h[tid]);
}

// ---------------- bf16 MFMA GEMM (B^T), double-buffered global_load_lds ----------------
// 128x128 tile, BK=32, 4 waves (2x2), 4x4 frags of 16x16x32 per wave.
// Pipeline: STAGE(next) -> counted vmcnt (6/4, never 0 mid-loop) -> s_barrier ->
//           ds_read+MFMA(cur) -> s_barrier.  Loads stay in flight across barriers.
// DUAL=1: two B matrices, epilogue Hb = silu(C1)*C3 (bf16). DUAL=0: Cf = C (f32).
template<int DUAL>
__global__ __launch_bounds__(256,1) void gemm_k(
    const unsigned short* __restrict__ A,
    const unsigned short* __restrict__ B1,
    const unsigned short* __restrict__ B3,
    unsigned short* __restrict__ Hb,
    float* __restrict__ Cf,
    int M, int N, int K)
{
  __shared__ unsigned short As [2][128*32];
  __shared__ unsigned short Bs [2][128*32];
  __shared__ unsigned short Bs3[DUAL?2:1][DUAL?128*32:16];
  const int tid  = threadIdx.x;
  const int lane = tid & 63;
  const int wave = tid >> 6;
  const int nbn  = N >> 7;
  const int bm   = blockIdx.x / nbn;
  const int bn   = blockIdx.x % nbn;
  const size_t m0 = (size_t)bm * 128;
  const size_t n0 = (size_t)bn * 128;
  const int wr = wave >> 1, wc = wave & 1;

  fx4 zero = {0.f,0.f,0.f,0.f};
  fx4 acc1[4][4], acc3[4][4];
  #pragma unroll
  for (int i=0;i<4;i++)
    #pragma unroll
    for (int j=0;j<4;j++){ acc1[i][j] = zero; if (DUAL) acc3[i][j] = zero; }

  const int c0 = tid, c1 = tid + 256;     // 512 chunks of 8 bf16 cover 128x32
  const int r0 = c0 >> 2, kc0 = c0 & 3;
  const int r1 = c1 >> 2, kc1 = c1 & 3;
  const unsigned short* Ab  = A  + m0*(size_t)K;
  const unsigned short* B1b = B1 + n0*(size_t)K;
  const unsigned short* B3b = DUAL ? (B3 + n0*(size_t)K) : (const unsigned short*)0;
  const int fr = lane & 15;
  const int fk = (lane >> 4) * 8;

  auto STAGE = [&](int buf, int k0){
    GLOAD16(Ab  + (size_t)r0*K + k0 + kc0*8, &As [buf][c0*8]);
    GLOAD16(Ab  + (size_t)r1*K + k0 + kc1*8, &As [buf][c1*8]);
    GLOAD16(B1b + (size_t)r0*K + k0 + kc0*8, &Bs [buf][c0*8]);
    GLOAD16(B1b + (size_t)r1*K + k0 + kc1*8, &Bs [buf][c1*8]);
    if (DUAL){
      GLOAD16(B3b + (size_t)r0*K + k0 + kc0*8, &Bs3[buf][c0*8]);
      GLOAD16(B3b + (size_t)r1*K + k0 + kc1*8, &Bs3[buf][c1*8]);
    }
  };

  const int nt = K >> 5;
  STAGE(0, 0);
  for (int t=0; t<nt; ++t){
    const int cur = t & 1;
    if (t+1 < nt){
      STAGE(cur^1, (t+1) << 5);
      if (DUAL) asm volatile("s_waitcnt vmcnt(6)" ::: "memory");
      else      asm volatile("s_waitcnt vmcnt(4)" ::: "memory");
    } else {
      asm volatile("s_waitcnt vmcnt(0)" ::: "memory");
    }
    __builtin_amdgcn_s_barrier();
    asm volatile("" ::: "memory");      // keep LDS reads below the barrier
    bfx8 af[4], b1f[4], b3f[4];
    #pragma unroll
    for (int m=0;m<4;m++) af[m]  = *(const bfx8*)&As[cur][(wr*64 + m*16 + fr)*32 + fk];
    #pragma unroll
    for (int n=0;n<4;n++){
      b1f[n] = *(const bfx8*)&Bs[cur][(wc*64 + n*16 + fr)*32 + fk];
      if (DUAL) b3f[n] = *(const bfx8*)&Bs3[cur][(wc*64 + n*16 + fr)*32 + fk];
    }
    #pragma unroll
    for (int m=0;m<4;m++)
      #pragma unroll
      for (int n=0;n<4;n++){
        acc1[m][n] = __builtin_amdgcn_mfma_f32_16x16x32_bf16(af[m], b1f[n], acc1[m][n], 0, 0, 0);
        if (DUAL)
          acc3[m][n] = __builtin_amdgcn_mfma_f32_16x16x32_bf16(af[m], b3f[n], acc3[m][n], 0, 0, 0);
      }
    asm volatile("" ::: "memory");      // keep LDS reads above the end barrier
    __builtin_amdgcn_s_barrier();
  }

  const int rs = (lane >> 4) * 4;   // C/D: row=(l>>4)*4+r, col=l&15  [m89]
  #pragma unroll
  for (int m=0;m<4;m++){
    #pragma unroll
    for (int n=0;n<4;n++){
      #pragma unroll
      for (int r=0;r<4;r++){
        size_t row = m0 + wr*64 + m*16 + rs + r;
        size_t col = n0 + wc*64 + n*16 + fr;
        size_t idx = row*(size_t)N + col;
        if (DUAL){
          float a = acc1[m][n][r];
          float c = acc3[m][n][r];
          float hsw = (a / (1.f + expf(-a))) * c;   // silu(C1)*C3
          Hb[idx] = f2bf(hsw);
        } else {
          Cf[idx] = acc1[m][n][r];
        }
      }
    }
  }
}

// ---------------- P-GEMVs: P1[f][e][j]=x[f]@w1[e][:,j], P3 same for w3 ----------------
__global__ __launch_bounds__(256) void pgemv_k(const float* __restrict__ x,
    const float* __restrict__ w1, const float* __restrict__ w3,
    float* __restrict__ P1, float* __restrict__ P3)
{
  __shared__ float xs[8*DIM];          // tokens 0..7 = first 8192 floats of x
  __shared__ float red[8][32][16];
  int e  = blockIdx.x >> 4;
  int jc = blockIdx.x & 15;
  int t  = threadIdx.x;
  for (int q=t; q<2048; q+=256) ((float4*)xs)[q] = ((const float4*)x)[q];
  __syncthreads();
  int j  = jc*32 + (t & 31);
  int kp = t >> 5;                      // 0..7, 128 k each
  float a1[8], a3[8];
  #pragma unroll
  for (int f=0;f<8;f++){ a1[f]=0.f; a3[f]=0.f; }
  const float* w1p = w1 + (size_t)e*DIM*HID + j;
  const float* w3p = w3 + (size_t)e*DIM*HID + j;
  #pragma unroll 4
  for (int k=kp*128; k<kp*128+128; ++k){
    float w1v = w1p[(size_t)k*HID];
    float w3v = w3p[(size_t)k*HID];
    #pragma unroll
    for (int f=0;f<8;f++){
      float xv = xs[f*DIM + k];
      a1[f] += xv*w1v;
      a3[f] += xv*w3v;
    }
  }
  #pragma unroll
  for (int f=0;f<8;f++){ red[kp][t&31][f] = a1[f]; red[kp][t&31][8+f] = a3[f]; }
  __syncthreads();
  if (kp==0){
    #pragma unroll
    for (int f=0;f<8;f++){
      float s1=0.f, s3=0.f;
      #pragma unroll
      for (int q=0;q<8;q++){ s1 += red[q][t][f]; s3 += red[q][t][8+f]; }
      P1[((size_t)f*8 + e)*HID + j] = s1;
      P3[((size_t)f*8 + e)*HID + j] = s3;
    }
  }
}

// ---------------- scatter rows into (f, eid) buckets (cumsum in-register) ----------------
__global__ __launch_bounds__(256) void scat_k(const int* __restrict__ topk,
    const float* __restrict__ wts, const int* __restrict__ counts,
    int* __restrict__ bcount, float* __restrict__ bw)
{
  int i = blockIdx.x*256 + threadIdx.x;
  if (i >= NROW) return;
  int offv[NE]; int s=0;
  #pragma unroll
  for (int q=0;q<NE;q++){ s += counts[q]; offv[q]=s; }   // inclusive cumsum
  int f = topk[i];
  int e = 0;
  #pragma unroll
  for (int q=0;q<NE;q++) if (i >= offv[q]) e = q+1;      // searchsorted right
  float w = wts[i];
  int b = f*8 + e;
  int slot = atomicAdd(&bcount[b], 1);
  bw[(size_t)b*NROW + slot] = w;
}

// ---------------- per-bucket silu-weighted sums: H[r][e][j] ----------------
__global__ __launch_bounds__(256) void bsum_k(const float* __restrict__ P1,
    const float* __restrict__ P3, const int* __restrict__ bcount,
    const float* __restrict__ bw, float* __restrict__ H)
{
  int b = blockIdx.x;        // r*8+e
  int t = threadIdx.x;
  int n = bcount[b];
  float a0 = P1[(size_t)b*HID + t];
  float a1 = P1[(size_t)b*HID + t + 256];
  float s0 = 0.f, s1 = 0.f;
  const float* wp = bw + (size_t)b*NROW;
  for (int q=0;q<n;q++){
    float w = wp[q];
    float z0 = w*a0, z1 = w*a1;
    s0 += w * z0 / (1.f + expf(-z0));   // w * silu(w*a)
    s1 += w * z1 / (1.f + expf(-z1));
  }
  H[(size_t)b*HID + t]       = P3[(size_t)b*HID + t]       * s0;
  H[(size_t)b*HID + t + 256] = P3[(size_t)b*HID + t + 256] * s1;
}

// ---------------- routed out: out[r][d] += sum_e H[r][e] @ w2[e][:,d] ----------------
__global__ __launch_bounds__(256) void rout_k(const float* __restrict__ H,
    const float* __restrict__ w2, float* __restrict__ out)
{
  __shared__ float Hs[8*HID];          // 16KB
  __shared__ float red[4][64][8];      // 8KB
  int e  = blockIdx.x >> 4;
  int dc = blockIdx.x & 15;
  int t  = threadIdx.x;
  for (int q=t; q<8*HID; q+=256){
    int r = q >> 9; int j = q & 511;
    Hs[q] = H[((size_t)r*8 + e)*HID + j];
  }
  __syncthreads();
  int d  = dc*64 + (t & 63);
  int jp = t >> 6;                      // 0..3, 128 j each
  float acc[8];
  #pragma unroll
  for (int r=0;r<8;r++) acc[r]=0.f;
  const float* w2p = w2 + (size_t)e*HID*DIM + d;
  #pragma unroll 4
  for (int j=jp*128; j<jp*128+128; ++j){
    float wv = w2p[(size_t)j*DIM];
    #pragma unroll
    for (int r=0;r<8;r++) acc[r] += Hs[r*HID + j]*wv;
  }
  #pragma unroll
  for (int r=0;r<8;r++) red[jp][t&63][r] = acc[r];
  __syncthreads();
  if (jp==0){
    #pragma unroll
    for (int r=0;r<8;r++){
      float v = red[0][t][r] + red[1][t][r] + red[2][t][r] + red[3][t][r];
      atomicAdd(&out[(size_t)r*DIM + d], v);
    }
  }
}

extern "C" void kernel_launch(void* const* d_in, const int* in_sizes, int n_in,
                              void* d_out, int out_size, void* d_ws, size_t ws_size,
                              hipStream_t stream)
{
  const float* x    = (const float*)d_in[0];
  const float* wg   = (const float*)d_in[1];
  const float* w1   = (const float*)d_in[2];
  const float* w2   = (const float*)d_in[3];   // NOTE: w2 before w3 in dict order
  const float* w3   = (const float*)d_in[4];
  const float* sw1  = (const float*)d_in[5];
  const float* sw2  = (const float*)d_in[6];   // sw2 before sw3
  const float* sw3  = (const float*)d_in[7];
  const float* bias = (const float*)d_in[8];
  float* out = (float*)d_out;

  char* wsp = (char*)d_ws;
  size_t off = 0;
  auto alloc = [&](size_t bytes)->char*{
    char* p = wsp + off; off += (bytes + 255) & ~(size_t)255; return p;
  };
  unsigned short* xb   = (unsigned short*)alloc((size_t)NTOK*DIM*2);
  unsigned short* s1b  = (unsigned short*)alloc((size_t)SHID*DIM*2);
  unsigned short* s3b  = (unsigned short*)alloc((size_t)SHID*DIM*2);
  unsigned short* s2b  = (unsigned short*)alloc((size_t)DIM*SHID*2);
  unsigned short* hb   = (unsigned short*)alloc((size_t)NTOK*SHID*2);
  float*          lgt  = (float*)alloc((size_t)NTOK*NE*4);
  int*            topk = (int*)alloc(NROW*4);
  float*          wtsb = (float*)alloc(NROW*4);
  int*            cnts = (int*)alloc(64);
  int*            bcnt = (int*)alloc(256);
  float*          P1   = (float*)alloc(64*HID*4);
  float*          P3   = (float*)alloc(64*HID*4);
  float*          Hbuf = (float*)alloc(64*HID*4);
  float*          bwb  = (float*)alloc((size_t)64*NROW*4);
  (void)ws_size; (void)in_sizes; (void)n_in; (void)out_size;

  const int NX = (NTOK*DIM)/4, NW = (SHID*DIM)/4;
  cvtall_k<<<(NX+3*NW)/256, 256, 0, stream>>>(x, sw1, sw3, sw2, xb, s1b, s3b, s2b);
  logits_k<<<NTOK/4, 256, 0, stream>>>(x, wg, lgt, cnts, bcnt);
  topk_k<<<NTOK/256, 256, 0, stream>>>(lgt, bias, topk, wtsb, cnts);

  // fused shared-expert FFN: hb = silu(x@sw1^T) * (x@sw3^T), then out = hb@sw2^T
  gemm_k<1><<<(NTOK/128)*(SHID/128), 256, 0, stream>>>(xb, s1b, s3b, hb, nullptr, NTOK, SHID, DIM);
  gemm_k<0><<<(NTOK/128)*(DIM/128),  256, 0, stream>>>(hb, s2b, nullptr, nullptr, out, NTOK, DIM, SHID);

  pgemv_k<<<128, 256, 0, stream>>>(x, w1, w3, P1, P3);
  scat_k<<<NROW/256, 256, 0, stream>>>(topk, wtsb, cnts, bcnt, bwb);
  bsum_k<<<64, 256, 0, stream>>>(P1, P3, bcnt, bwb, Hbuf);
  rout_k<<<128, 256, 0, stream>>>(Hbuf, w2, out);
}

// Round 5
// 241.927 us; speedup vs baseline: 1.7286x; 1.2040x over previous
//
#include <hip/hip_runtime.h>
#include <math.h>

#define DIM  1024
#define HID  512
#define SHID 1024
#define NTOK 4096
#define NE   8
#define NROW 8192   // NTOK * TOPK

typedef __attribute__((ext_vector_type(8))) short  bfx8;   // 8 bf16 (4 VGPRs)
typedef __attribute__((ext_vector_type(4))) float  fx4;

__device__ __forceinline__ unsigned short f2bf(float f){
  unsigned int u = __float_as_uint(f);
  unsigned int r = (u + 0x7FFFu + ((u >> 16) & 1u)) >> 16;
  return (unsigned short)r;
}

#define GLOAD16(g, l) __builtin_amdgcn_global_load_lds( \
    (const __attribute__((address_space(1))) unsigned int*)(g), \
    (__attribute__((address_space(3))) unsigned int*)(l), 16, 0, 0)

// ---------------- f32 -> bf16 convert for sw1, sw3, sw2 ----------------
__global__ __launch_bounds__(256) void cvtall_k(
    const float* __restrict__ sw1, const float* __restrict__ sw3,
    const float* __restrict__ sw2, unsigned short* __restrict__ s1b,
    unsigned short* __restrict__ s3b, unsigned short* __restrict__ s2b)
{
  const int NW = (SHID*DIM)/4;     // 262144 float4 per weight
  int i = blockIdx.x*256 + threadIdx.x;
  const float* s; unsigned short* d; int j;
  if (i < NW)            { s = sw1; d = s1b; j = i; }
  else if (i < 2*NW)     { s = sw3; d = s3b; j = i-NW; }
  else                   { s = sw2; d = s2b; j = i-2*NW; }
  float4 v = ((const float4*)s)[j];
  ushort4 o;
  o.x = f2bf(v.x); o.y = f2bf(v.y); o.z = f2bf(v.z); o.w = f2bf(v.w);
  ((ushort4*)d)[j] = o;
}

// ---------------- logits: wave per token; also emits xb (bf16 x); blk0 zeroes counters ----
__global__ __launch_bounds__(256) void logits_k(const float* __restrict__ x,
    const float* __restrict__ wg, float* __restrict__ logits,
    unsigned short* __restrict__ xb, int* __restrict__ counts, int* __restrict__ bcount)
{
  if (blockIdx.x == 0 && threadIdx.x < 64){
    if (threadIdx.x < NE) counts[threadIdx.x] = 0;
    bcount[threadIdx.x] = 0;
  }
  int w = threadIdx.x >> 6, l = threadIdx.x & 63;
  int t = blockIdx.x*4 + w;
  const float4* xr = (const float4*)(x + (size_t)t*DIM);
  ushort4* xw = (ushort4*)xb + (size_t)t*256;
  float acc[NE];
  #pragma unroll
  for (int e=0;e<NE;e++) acc[e]=0.f;
  #pragma unroll
  for (int it=0; it<4; ++it){
    int idx = l + it*64;
    float4 xv = xr[idx];
    ushort4 o;
    o.x = f2bf(xv.x); o.y = f2bf(xv.y); o.z = f2bf(xv.z); o.w = f2bf(xv.w);
    xw[idx] = o;
    #pragma unroll
    for (int e=0;e<NE;e++){
      float4 wv = ((const float4*)(wg + (size_t)e*DIM))[idx];
      acc[e] += xv.x*wv.x + xv.y*wv.y + xv.z*wv.z + xv.w*wv.w;
    }
  }
  #pragma unroll
  for (int off=32; off>=1; off>>=1){
    #pragma unroll
    for (int e=0;e<NE;e++) acc[e] += __shfl_xor(acc[e], off, 64);
  }
  if (l==0){
    float4 a = {acc[0],acc[1],acc[2],acc[3]};
    float4 b = {acc[4],acc[5],acc[6],acc[7]};
    ((float4*)(logits + (size_t)t*8))[0] = a;
    ((float4*)(logits + (size_t)t*8))[1] = b;
  }
}

// ---------------- top-k: thread per token; LDS histogram; also zeroes S ----------------
__global__ __launch_bounds__(256) void topk_k(const float* __restrict__ logits,
    const float* __restrict__ bias, int* __restrict__ topk,
    float* __restrict__ wts, int* __restrict__ counts, float* __restrict__ S)
{
  __shared__ int h[NE];
  int tid = threadIdx.x;
  if (tid < NE) h[tid] = 0;
  int i = blockIdx.x*256 + tid;
  float4 z4 = {0.f,0.f,0.f,0.f};
  ((float4*)S)[i*2]   = z4;     // 16 blocks x 256 thr x 8 floats = 32768 = 64*512
  ((float4*)S)[i*2+1] = z4;
  __syncthreads();
  float4 la = ((const float4*)(logits + (size_t)i*8))[0];
  float4 lb = ((const float4*)(logits + (size_t)i*8))[1];
  float lg[NE] = {la.x,la.y,la.z,la.w,lb.x,lb.y,lb.z,lb.w};
  float m = lg[0];
  #pragma unroll
  for (int e=1;e<NE;e++) m = fmaxf(m, lg[e]);
  float p[NE], s=0.f;
  #pragma unroll
  for (int e=0;e<NE;e++){ p[e]=expf(lg[e]-m); s+=p[e]; }
  float inv = 1.f/s;
  float sc[NE], sb[NE];
  #pragma unroll
  for (int e=0;e<NE;e++){ sc[e]=p[e]*inv; sb[e]=sc[e]+bias[e]; }
  float gs[4];
  #pragma unroll
  for (int g=0; g<4; g++) gs[g] = sb[2*g] + sb[2*g+1];   // top-2 of 2 == sum
  int g1=0;
  #pragma unroll
  for (int g=1; g<4; g++) if (gs[g] > gs[g1]) g1=g;      // ties -> lower idx
  int g2=-1;
  #pragma unroll
  for (int g=0; g<4; g++){ if (g==g1) continue; if (g2<0 || gs[g]>gs[g2]) g2=g; }
  int e1=-1, e2=-1;
  #pragma unroll
  for (int e=0;e<NE;e++){
    int g=e>>1; if (g!=g1 && g!=g2) continue;
    if (e1<0 || sb[e]>sb[e1]) e1=e;
  }
  #pragma unroll
  for (int e=0;e<NE;e++){
    int g=e>>1; if (g!=g1 && g!=g2) continue;
    if (e==e1) continue;
    if (e2<0 || sb[e]>sb[e2]) e2=e;
  }
  topk[2*i]   = e1;  topk[2*i+1] = e2;
  wts[2*i]    = sc[e1];  wts[2*i+1] = sc[e2];
  atomicAdd(&h[e1], 1);
  atomicAdd(&h[e2], 1);
  __syncthreads();
  if (tid < NE) atomicAdd(&counts[tid], h[tid]);
}

// ---------------- bf16 MFMA GEMM (B^T), 8 waves, double-buffered global_load_lds ------
// 128x128 tile, BK=32, 8 waves (2x4): wave owns 64x32. Counted vmcnt, raw s_barrier.
// DUAL=1: two B mats, epilogue Hb = silu(C1)*C3 (bf16). DUAL=0: Cf = C (f32).
template<int DUAL>
__global__ __launch_bounds__(512,2) void gemm_k(
    const unsigned short* __restrict__ A,
    const unsigned short* __restrict__ B1,
    const unsigned short* __restrict__ B3,
    unsigned short* __restrict__ Hb,
    float* __restrict__ Cf,
    int M, int N, int K)
{
  __shared__ unsigned short As [2][128*32];
  __shared__ unsigned short Bs [2][128*32];
  __shared__ unsigned short Bs3[DUAL?2:1][DUAL?128*32:16];
  const int tid  = threadIdx.x;        // 0..511
  const int lane = tid & 63;
  const int wave = tid >> 6;           // 0..7
  const int nbn  = N >> 7;
  const int bm   = blockIdx.x / nbn;
  const int bn   = blockIdx.x % nbn;
  const size_t m0 = (size_t)bm * 128;
  const size_t n0 = (size_t)bn * 128;
  const int wr = wave >> 2;            // 0..1 -> 64 rows
  const int wc = wave & 3;             // 0..3 -> 32 cols

  fx4 zero = {0.f,0.f,0.f,0.f};
  fx4 acc1[4][2], acc3[4][2];
  #pragma unroll
  for (int i=0;i<4;i++)
    #pragma unroll
    for (int j=0;j<2;j++){ acc1[i][j] = zero; if (DUAL) acc3[i][j] = zero; }

  const int c0 = tid;                  // one 16B chunk per matrix per thread
  const int r0 = c0 >> 2, kc0 = c0 & 3;
  const unsigned short* Ab  = A  + m0*(size_t)K;
  const unsigned short* B1b = B1 + n0*(size_t)K;
  const unsigned short* B3b = DUAL ? (B3 + n0*(size_t)K) : (const unsigned short*)0;
  const int fr = lane & 15;
  const int fk = (lane >> 4) * 8;

  auto STAGE = [&](int buf, int k0){
    GLOAD16(Ab  + (size_t)r0*K + k0 + kc0*8, &As [buf][c0*8]);
    GLOAD16(B1b + (size_t)r0*K + k0 + kc0*8, &Bs [buf][c0*8]);
    if (DUAL) GLOAD16(B3b + (size_t)r0*K + k0 + kc0*8, &Bs3[buf][c0*8]);
  };

  const int nt = K >> 5;
  STAGE(0, 0);
  for (int t=0; t<nt; ++t){
    const int cur = t & 1;
    if (t+1 < nt){
      STAGE(cur^1, (t+1) << 5);
      if (DUAL) asm volatile("s_waitcnt vmcnt(3)" ::: "memory");
      else      asm volatile("s_waitcnt vmcnt(2)" ::: "memory");
    } else {
      asm volatile("s_waitcnt vmcnt(0)" ::: "memory");
    }
    __builtin_amdgcn_s_barrier();
    asm volatile("" ::: "memory");
    bfx8 af[4], b1f[2], b3f[2];
    #pragma unroll
    for (int m=0;m<4;m++) af[m]  = *(const bfx8*)&As[cur][(wr*64 + m*16 + fr)*32 + fk];
    #pragma unroll
    for (int n=0;n<2;n++){
      b1f[n] = *(const bfx8*)&Bs[cur][(wc*32 + n*16 + fr)*32 + fk];
      if (DUAL) b3f[n] = *(const bfx8*)&Bs3[cur][(wc*32 + n*16 + fr)*32 + fk];
    }
    #pragma unroll
    for (int m=0;m<4;m++)
      #pragma unroll
      for (int n=0;n<2;n++){
        acc1[m][n] = __builtin_amdgcn_mfma_f32_16x16x32_bf16(af[m], b1f[n], acc1[m][n], 0, 0, 0);
        if (DUAL)
          acc3[m][n] = __builtin_amdgcn_mfma_f32_16x16x32_bf16(af[m], b3f[n], acc3[m][n], 0, 0, 0);
      }
    asm volatile("" ::: "memory");
    __builtin_amdgcn_s_barrier();
  }

  const int rs = (lane >> 4) * 4;   // C/D: row=(l>>4)*4+r, col=l&15  [m89]
  #pragma unroll
  for (int m=0;m<4;m++){
    #pragma unroll
    for (int n=0;n<2;n++){
      #pragma unroll
      for (int r=0;r<4;r++){
        size_t row = m0 + wr*64 + m*16 + rs + r;
        size_t col = n0 + wc*32 + n*16 + fr;
        size_t idx = row*(size_t)N + col;
        if (DUAL){
          float a = acc1[m][n][r];
          float c = acc3[m][n][r];
          float hsw = (a / (1.f + expf(-a))) * c;   // silu(C1)*C3
          Hb[idx] = f2bf(hsw);
        } else {
          Cf[idx] = acc1[m][n][r];
        }
      }
    }
  }
}

// ---------------- P-GEMVs (k-split x2): P1h[kc][f*8+e][j] partials ----------------
// grid 256 = e(8) x jc(16) x kc(2); threads 256 = 32 j x 8 kp (64 k each)
__global__ __launch_bounds__(256) void pgemv_k(const float* __restrict__ x,
    const float* __restrict__ w1, const float* __restrict__ w3,
    float* __restrict__ P1, float* __restrict__ P3)
{
  __shared__ float xs[8*512];          // tokens 0..7, k-slice of 512
  __shared__ float red[8][32][16];
  int e  = blockIdx.x >> 5;
  int jc = (blockIdx.x >> 1) & 15;
  int kc = blockIdx.x & 1;
  int t  = threadIdx.x;
  for (int q=t; q<1024; q+=256){
    int f = q >> 7, k4 = q & 127;
    ((float4*)xs)[q] = ((const float4*)x)[f*256 + kc*128 + k4];
  }
  __syncthreads();
  int j  = jc*32 + (t & 31);
  int kp = t >> 5;                      // 0..7, 64 k each
  float a1[8], a3[8];
  #pragma unroll
  for (int f=0;f<8;f++){ a1[f]=0.f; a3[f]=0.f; }
  const float* w1p = w1 + (size_t)e*DIM*HID + (size_t)(kc*512)*HID + j;
  const float* w3p = w3 + (size_t)e*DIM*HID + (size_t)(kc*512)*HID + j;
  #pragma unroll 4
  for (int k=kp*64; k<kp*64+64; ++k){
    float w1v = w1p[(size_t)k*HID];
    float w3v = w3p[(size_t)k*HID];
    #pragma unroll
    for (int f=0;f<8;f++){
      float xv = xs[f*512 + k];
      a1[f] += xv*w1v;
      a3[f] += xv*w3v;
    }
  }
  #pragma unroll
  for (int f=0;f<8;f++){ red[kp][t&31][f] = a1[f]; red[kp][t&31][8+f] = a3[f]; }
  __syncthreads();
  if (kp==0){
    #pragma unroll
    for (int f=0;f<8;f++){
      float s1=0.f, s3=0.f;
      #pragma unroll
      for (int q=0;q<8;q++){ s1 += red[q][t][f]; s3 += red[q][t][8+f]; }
      P1[((size_t)(kc*64) + f*8 + e)*HID + j] = s1;
      P3[((size_t)(kc*64) + f*8 + e)*HID + j] = s3;
    }
  }
}

// ---------------- scatter rows into (f, eid) buckets (cumsum in-register) ----------------
__global__ __launch_bounds__(256) void scat_k(const int* __restrict__ topk,
    const float* __restrict__ wts, const int* __restrict__ counts,
    int* __restrict__ bcount, float* __restrict__ bw)
{
  int i = blockIdx.x*256 + threadIdx.x;
  if (i >= NROW) return;
  int offv[NE]; int s=0;
  #pragma unroll
  for (int q=0;q<NE;q++){ s += counts[q]; offv[q]=s; }   // inclusive cumsum
  int f = topk[i];
  int e = 0;
  #pragma unroll
  for (int q=0;q<NE;q++) if (i >= offv[q]) e = q+1;      // searchsorted right
  float w = wts[i];
  int b = f*8 + e;
  int slot = atomicAdd(&bcount[b], 1);
  bw[(size_t)b*NROW + slot] = w;
}

// ---------------- partial silu-weighted sums: S[b][j] += sum_q w silu(w*a) ----------------
// grid 512 = b(64) x chunk(8); threads 256, 2 cols each
__global__ __launch_bounds__(256) void ssum_k(const float* __restrict__ P1,
    const int* __restrict__ bcount, const float* __restrict__ bw,
    float* __restrict__ S)
{
  int b = blockIdx.x >> 3;
  int c = blockIdx.x & 7;
  int t = threadIdx.x;
  int n = bcount[b];
  float a0 = P1[(size_t)b*HID + t]       + P1[(size_t)(64+b)*HID + t];
  float a1 = P1[(size_t)b*HID + t + 256] + P1[(size_t)(64+b)*HID + t + 256];
  float s0 = 0.f, s1 = 0.f;
  const float* wp = bw + (size_t)b*NROW;
  for (int q=c; q<n; q+=8){
    float w = wp[q];
    float z0 = w*a0, z1 = w*a1;
    s0 += w * z0 / (1.f + expf(-z0));   // w * silu(w*a)
    s1 += w * z1 / (1.f + expf(-z1));
  }
  if (n > c){
    atomicAdd(&S[(size_t)b*HID + t],       s0);
    atomicAdd(&S[(size_t)b*HID + t + 256], s1);
  }
}

// ---------------- routed out: out[r][d] += sum_e (P3[r,e]*S[r,e]) @ w2[e][:,d] ---------
// grid 256 = e(8) x dc(16) x jh(2); threads 256 = 64 d x 4 jp (64 j each)
__global__ __launch_bounds__(256) void rout_k(const float* __restrict__ P3,
    const float* __restrict__ S, const float* __restrict__ w2,
    float* __restrict__ out)
{
  __shared__ float Hs[8*256];          // 8KB
  __shared__ float red[4][64][8];      // 8KB
  int e  = blockIdx.x >> 5;
  int dc = (blockIdx.x >> 1) & 15;
  int jh = blockIdx.x & 1;
  int t  = threadIdx.x;
  for (int q=t; q<2048; q+=256){
    int r = q >> 8; int jl = q & 255;
    size_t idx = (size_t)(r*8 + e)*HID + jh*256 + jl;
    Hs[q] = (P3[idx] + P3[(size_t)64*HID + idx]) * S[idx];
  }
  __syncthreads();
  int d  = dc*64 + (t & 63);
  int jp = t >> 6;                      // 0..3, 64 j each
  float acc[8];
  #pragma unroll
  for (int r=0;r<8;r++) acc[r]=0.f;
  const float* w2p = w2 + (size_t)e*HID*DIM + (size_t)(jh*256)*DIM + d;
  #pragma unroll 4
  for (int jl=jp*64; jl<jp*64+64; ++jl){
    float wv = w2p[(size_t)jl*DIM];
    #pragma unroll
    for (int r=0;r<8;r++) acc[r] += Hs[r*256 + jl]*wv;
  }
  #pragma unroll
  for (int r=0;r<8;r++) red[jp][t&63][r] = acc[r];
  __syncthreads();
  if (jp==0){
    #pragma unroll
    for (int r=0;r<8;r++){
      float v = red[0][t][r] + red[1][t][r] + red[2][t][r] + red[3][t][r];
      atomicAdd(&out[(size_t)r*DIM + d], v);
    }
  }
}

extern "C" void kernel_launch(void* const* d_in, const int* in_sizes, int n_in,
                              void* d_out, int out_size, void* d_ws, size_t ws_size,
                              hipStream_t stream)
{
  const float* x    = (const float*)d_in[0];
  const float* wg   = (const float*)d_in[1];
  const float* w1   = (const float*)d_in[2];
  const float* w2   = (const float*)d_in[3];   // NOTE: w2 before w3 in dict order
  const float* w3   = (const float*)d_in[4];
  const float* sw1  = (const float*)d_in[5];
  const float* sw2  = (const float*)d_in[6];   // sw2 before sw3
  const float* sw3  = (const float*)d_in[7];
  const float* bias = (const float*)d_in[8];
  float* out = (float*)d_out;

  char* wsp = (char*)d_ws;
  size_t off = 0;
  auto alloc = [&](size_t bytes)->char*{
    char* p = wsp + off; off += (bytes + 255) & ~(size_t)255; return p;
  };
  unsigned short* xb   = (unsigned short*)alloc((size_t)NTOK*DIM*2);
  unsigned short* s1b  = (unsigned short*)alloc((size_t)SHID*DIM*2);
  unsigned short* s3b  = (unsigned short*)alloc((size_t)SHID*DIM*2);
  unsigned short* s2b  = (unsigned short*)alloc((size_t)DIM*SHID*2);
  unsigned short* hb   = (unsigned short*)alloc((size_t)NTOK*SHID*2);
  float*          lgt  = (float*)alloc((size_t)NTOK*NE*4);
  int*            topk = (int*)alloc(NROW*4);
  float*          wtsb = (float*)alloc(NROW*4);
  int*            cnts = (int*)alloc(64);
  int*            bcnt = (int*)alloc(256);
  float*          P1   = (float*)alloc(2*64*HID*4);
  float*          P3   = (float*)alloc(2*64*HID*4);
  float*          Sbuf = (float*)alloc(64*HID*4);
  float*          bwb  = (float*)alloc((size_t)64*NROW*4);
  (void)ws_size; (void)in_sizes; (void)n_in; (void)out_size;

  const int NW = (SHID*DIM)/4;
  cvtall_k<<<(3*NW)/256, 256, 0, stream>>>(sw1, sw3, sw2, s1b, s3b, s2b);
  logits_k<<<NTOK/4, 256, 0, stream>>>(x, wg, lgt, xb, cnts, bcnt);
  topk_k<<<NTOK/256, 256, 0, stream>>>(lgt, bias, topk, wtsb, cnts, Sbuf);
  scat_k<<<NROW/256, 256, 0, stream>>>(topk, wtsb, cnts, bcnt, bwb);
  pgemv_k<<<256, 256, 0, stream>>>(x, w1, w3, P1, P3);
  ssum_k<<<512, 256, 0, stream>>>(P1, bcnt, bwb, Sbuf);

  // fused shared-expert FFN: hb = silu(x@sw1^T) * (x@sw3^T), then out = hb@sw2^T
  gemm_k<1><<<(NTOK/128)*(SHID/128), 512, 0, stream>>>(xb, s1b, s3b, hb, nullptr, NTOK, SHID, DIM);
  gemm_k<0><<<(NTOK/128)*(DIM/128),  512, 0, stream>>>(hb, s2b, nullptr, nullptr, out, NTOK, DIM, SHID);

  rout_k<<<256, 256, 0, stream>>>(P3, Sbuf, w2, out);
}

// Round 7
// 233.652 us; speedup vs baseline: 1.7898x; 1.0354x over previous
//
#include <hip/hip_runtime.h>
#include <math.h>

#define DIM  1024
#define HID  512
#define SHID 1024
#define NTOK 4096
#define NE   8
#define NROW 8192   // NTOK * TOPK

typedef __attribute__((ext_vector_type(8))) short  bfx8;   // 8 bf16 (4 VGPRs)
typedef __attribute__((ext_vector_type(4))) float  fx4;

__device__ __forceinline__ unsigned short f2bf(float f){
  unsigned int u = __float_as_uint(f);
  unsigned int r = (u + 0x7FFFu + ((u >> 16) & 1u)) >> 16;
  return (unsigned short)r;
}

#define GLOAD16(g, l) __builtin_amdgcn_global_load_lds( \
    (const __attribute__((address_space(1))) unsigned int*)(g), \
    (__attribute__((address_space(3))) unsigned int*)(l), 16, 0, 0)

// ---------------- f32 -> bf16 convert for sw1, sw3, sw2 ----------------
__global__ __launch_bounds__(256) void cvtall_k(
    const float* __restrict__ sw1, const float* __restrict__ sw3,
    const float* __restrict__ sw2, unsigned short* __restrict__ s1b,
    unsigned short* __restrict__ s3b, unsigned short* __restrict__ s2b)
{
  const int NW = (SHID*DIM)/4;     // 262144 float4 per weight
  int i = blockIdx.x*256 + threadIdx.x;
  const float* s; unsigned short* d; int j;
  if (i < NW)            { s = sw1; d = s1b; j = i; }
  else if (i < 2*NW)     { s = sw3; d = s3b; j = i-NW; }
  else                   { s = sw2; d = s2b; j = i-2*NW; }
  float4 v = ((const float4*)s)[j];
  ushort4 o;
  o.x = f2bf(v.x); o.y = f2bf(v.y); o.z = f2bf(v.z); o.w = f2bf(v.w);
  ((ushort4*)d)[j] = o;
}

// ---------------- logits: wave per token; also emits xb (bf16 x); blk0 zeroes counters ----
__global__ __launch_bounds__(256) void logits_k(const float* __restrict__ x,
    const float* __restrict__ wg, float* __restrict__ logits,
    unsigned short* __restrict__ xb, int* __restrict__ counts, int* __restrict__ bcount)
{
  if (blockIdx.x == 0 && threadIdx.x < 64){
    if (threadIdx.x < NE) counts[threadIdx.x] = 0;
    bcount[threadIdx.x] = 0;
  }
  int w = threadIdx.x >> 6, l = threadIdx.x & 63;
  int t = blockIdx.x*4 + w;
  const float4* xr = (const float4*)(x + (size_t)t*DIM);
  ushort4* xw = (ushort4*)xb + (size_t)t*256;
  float acc[NE];
  #pragma unroll
  for (int e=0;e<NE;e++) acc[e]=0.f;
  #pragma unroll
  for (int it=0; it<4; ++it){
    int idx = l + it*64;
    float4 xv = xr[idx];
    ushort4 o;
    o.x = f2bf(xv.x); o.y = f2bf(xv.y); o.z = f2bf(xv.z); o.w = f2bf(xv.w);
    xw[idx] = o;
    #pragma unroll
    for (int e=0;e<NE;e++){
      float4 wv = ((const float4*)(wg + (size_t)e*DIM))[idx];
      acc[e] += xv.x*wv.x + xv.y*wv.y + xv.z*wv.z + xv.w*wv.w;
    }
  }
  #pragma unroll
  for (int off=32; off>=1; off>>=1){
    #pragma unroll
    for (int e=0;e<NE;e++) acc[e] += __shfl_xor(acc[e], off, 64);
  }
  if (l==0){
    float4 a = {acc[0],acc[1],acc[2],acc[3]};
    float4 b = {acc[4],acc[5],acc[6],acc[7]};
    ((float4*)(logits + (size_t)t*8))[0] = a;
    ((float4*)(logits + (size_t)t*8))[1] = b;
  }
}

// ---------------- top-k: thread per token; LDS histogram; also zeroes S ----------------
__global__ __launch_bounds__(256) void topk_k(const float* __restrict__ logits,
    const float* __restrict__ bias, int* __restrict__ topk,
    float* __restrict__ wts, int* __restrict__ counts, float* __restrict__ S)
{
  __shared__ int h[NE];
  int tid = threadIdx.x;
  if (tid < NE) h[tid] = 0;
  int i = blockIdx.x*256 + tid;
  float4 z4 = {0.f,0.f,0.f,0.f};
  ((float4*)S)[i*2]   = z4;     // 16 blocks x 256 thr x 8 floats = 32768 = 64*512
  ((float4*)S)[i*2+1] = z4;
  __syncthreads();
  float4 la = ((const float4*)(logits + (size_t)i*8))[0];
  float4 lb = ((const float4*)(logits + (size_t)i*8))[1];
  float lg[NE] = {la.x,la.y,la.z,la.w,lb.x,lb.y,lb.z,lb.w};
  float m = lg[0];
  #pragma unroll
  for (int e=1;e<NE;e++) m = fmaxf(m, lg[e]);
  float p[NE], s=0.f;
  #pragma unroll
  for (int e=0;e<NE;e++){ p[e]=expf(lg[e]-m); s+=p[e]; }
  float inv = 1.f/s;
  float sc[NE], sb[NE];
  #pragma unroll
  for (int e=0;e<NE;e++){ sc[e]=p[e]*inv; sb[e]=sc[e]+bias[e]; }
  float gs[4];
  #pragma unroll
  for (int g=0; g<4; g++) gs[g] = sb[2*g] + sb[2*g+1];   // top-2 of 2 == sum
  int g1=0;
  #pragma unroll
  for (int g=1; g<4; g++) if (gs[g] > gs[g1]) g1=g;      // ties -> lower idx
  int g2=-1;
  #pragma unroll
  for (int g=0; g<4; g++){ if (g==g1) continue; if (g2<0 || gs[g]>gs[g2]) g2=g; }
  int e1=-1, e2=-1;
  #pragma unroll
  for (int e=0;e<NE;e++){
    int g=e>>1; if (g!=g1 && g!=g2) continue;
    if (e1<0 || sb[e]>sb[e1]) e1=e;
  }
  #pragma unroll
  for (int e=0;e<NE;e++){
    int g=e>>1; if (g!=g1 && g!=g2) continue;
    if (e==e1) continue;
    if (e2<0 || sb[e]>sb[e2]) e2=e;
  }
  topk[2*i]   = e1;  topk[2*i+1] = e2;
  wts[2*i]    = sc[e1];  wts[2*i+1] = sc[e2];
  atomicAdd(&h[e1], 1);
  atomicAdd(&h[e2], 1);
  __syncthreads();
  if (tid < NE) atomicAdd(&counts[tid], h[tid]);
}

// ---------------- bf16 MFMA GEMM (B^T), 8 waves, BK=64, dbuf, XOR-swizzled LDS --------
// 128x128 tile, BK=64, 8 waves (2x4): wave owns 64 rows x 32 cols.
// Staging: linear LDS dest + inverse-swizzled GLOBAL source (kc^(row&7));
// read applies the same XOR -> bank-conflict-free ds_read_b128 (T2, rule #21).
// Counted vmcnt (6 dual / 4 single), raw s_barrier. XCD-chunked block swizzle (T1).
// DUAL=1: two B mats, epilogue Hb = silu(C1)*C3 (bf16). DUAL=0: Cf = C (f32).
template<int DUAL>
__global__ __launch_bounds__(512,2) void gemm_k(
    const unsigned short* __restrict__ A,
    const unsigned short* __restrict__ B1,
    const unsigned short* __restrict__ B3,
    unsigned short* __restrict__ Hb,
    float* __restrict__ Cf,
    int M, int N, int K)
{
  __shared__ unsigned short As [2][128*64];
  __shared__ unsigned short Bs [2][128*64];
  __shared__ unsigned short Bs3[DUAL?2:1][DUAL?128*64:16];
  const int tid  = threadIdx.x;        // 0..511
  const int lane = tid & 63;
  const int wave = tid >> 6;           // 0..7
  const int nbn  = N >> 7;
  // XCD-chunked swizzle: 8 XCDs x (nwg/8) consecutive blocks each (grid=256 -> bijective)
  const int cpx  = gridDim.x >> 3;
  const int wg   = (blockIdx.x & 7)*cpx + (blockIdx.x >> 3);
  const int bm   = wg / nbn;
  const int bn   = wg % nbn;
  const size_t m0 = (size_t)bm * 128;
  const size_t n0 = (size_t)bn * 128;
  const int wr = wave >> 2;            // 0..1 -> 64 rows
  const int wc = wave & 3;             // 0..3 -> 32 cols

  fx4 zero = {0.f,0.f,0.f,0.f};
  fx4 acc1[4][2], acc3[4][2];
  #pragma unroll
  for (int i=0;i<4;i++)
    #pragma unroll
    for (int j=0;j<2;j++){ acc1[i][j] = zero; if (DUAL) acc3[i][j] = zero; }

  // staging: per matrix 1024 chunks of 8 bf16 (128 rows x 8 k-chunks); 2 per thread
  const int c0 = tid,        r0 = c0 >> 3, kc0 = c0 & 7;
  const int c1 = tid + 512,  r1 = c1 >> 3, kc1 = c1 & 7;
  const int sk0 = (kc0 ^ (r0 & 7)) * 8;   // inverse-swizzled global k-chunk
  const int sk1 = (kc1 ^ (r1 & 7)) * 8;
  const unsigned short* Ab  = A  + m0*(size_t)K;
  const unsigned short* B1b = B1 + n0*(size_t)K;
  const unsigned short* B3b = DUAL ? (B3 + n0*(size_t)K) : (const unsigned short*)0;
  const int fr = lane & 15;
  const int fq = lane >> 4;            // 0..3: k-subchunk within fragment

  auto STAGE = [&](int buf, int k0){
    GLOAD16(Ab  + (size_t)r0*K + k0 + sk0, &As [buf][c0*8]);
    GLOAD16(Ab  + (size_t)r1*K + k0 + sk1, &As [buf][c1*8]);
    GLOAD16(B1b + (size_t)r0*K + k0 + sk0, &Bs [buf][c0*8]);
    GLOAD16(B1b + (size_t)r1*K + k0 + sk1, &Bs [buf][c1*8]);
    if (DUAL){
      GLOAD16(B3b + (size_t)r0*K + k0 + sk0, &Bs3[buf][c0*8]);
      GLOAD16(B3b + (size_t)r1*K + k0 + sk1, &Bs3[buf][c1*8]);
    }
  };

  // swizzled LDS read offset (bf16 elements) for row, k-sub ks
  auto LOFF = [&](int row, int ks){
    return row*64 + ((((ks<<2) + fq) ^ (row & 7)) << 3);
  };

  const int nt = K >> 6;
  STAGE(0, 0);
  for (int t=0; t<nt; ++t){
    const int cur = t & 1;
    if (t+1 < nt){
      STAGE(cur^1, (t+1) << 6);
      if (DUAL) asm volatile("s_waitcnt vmcnt(6)" ::: "memory");
      else      asm volatile("s_waitcnt vmcnt(4)" ::: "memory");
    } else {
      asm volatile("s_waitcnt vmcnt(0)" ::: "memory");
    }
    __builtin_amdgcn_s_barrier();
    asm volatile("" ::: "memory");
    #pragma unroll
    for (int ks=0; ks<2; ++ks){
      bfx8 af[4], b1f[2], b3f[2];
      #pragma unroll
      for (int m=0;m<4;m++){
        int row = wr*64 + m*16 + fr;
        af[m] = *(const bfx8*)&As[cur][LOFF(row, ks)];
      }
      #pragma unroll
      for (int n=0;n<2;n++){
        int row = wc*32 + n*16 + fr;
        b1f[n] = *(const bfx8*)&Bs[cur][LOFF(row, ks)];
        if (DUAL) b3f[n] = *(const bfx8*)&Bs3[cur][LOFF(row, ks)];
      }
      #pragma unroll
      for (int m=0;m<4;m++)
        #pragma unroll
        for (int n=0;n<2;n++){
          acc1[m][n] = __builtin_amdgcn_mfma_f32_16x16x32_bf16(af[m], b1f[n], acc1[m][n], 0, 0, 0);
          if (DUAL)
            acc3[m][n] = __builtin_amdgcn_mfma_f32_16x16x32_bf16(af[m], b3f[n], acc3[m][n], 0, 0, 0);
        }
    }
    asm volatile("" ::: "memory");
    __builtin_amdgcn_s_barrier();
  }

  const int rs = (lane >> 4) * 4;   // C/D: row=(l>>4)*4+r, col=l&15  [m89]
  #pragma unroll
  for (int m=0;m<4;m++){
    #pragma unroll
    for (int n=0;n<2;n++){
      #pragma unroll
      for (int r=0;r<4;r++){
        size_t row = m0 + wr*64 + m*16 + rs + r;
        size_t col = n0 + wc*32 + n*16 + fr;
        size_t idx = row*(size_t)N + col;
        if (DUAL){
          float a = acc1[m][n][r];
          float c = acc3[m][n][r];
          float hsw = (a / (1.f + expf(-a))) * c;   // silu(C1)*C3
          Hb[idx] = f2bf(hsw);
        } else {
          Cf[idx] = acc1[m][n][r];
        }
      }
    }
  }
}

// ---------------- P-GEMVs (k-split x2): P1h[kc][f*8+e][j] partials ----------------
// grid 256 = e(8) x jc(16) x kc(2); threads 256 = 32 j x 8 kp (64 k each)
__global__ __launch_bounds__(256) void pgemv_k(const float* __restrict__ x,
    const float* __restrict__ w1, const float* __restrict__ w3,
    float* __restrict__ P1, float* __restrict__ P3)
{
  __shared__ float xs[8*512];          // tokens 0..7, k-slice of 512
  __shared__ float red[8][32][16];
  int e  = blockIdx.x >> 5;
  int jc = (blockIdx.x >> 1) & 15;
  int kc = blockIdx.x & 1;
  int t  = threadIdx.x;
  for (int q=t; q<1024; q+=256){
    int f = q >> 7, k4 = q & 127;
    ((float4*)xs)[q] = ((const float4*)x)[f*256 + kc*128 + k4];
  }
  __syncthreads();
  int j  = jc*32 + (t & 31);
  int kp = t >> 5;                      // 0..7, 64 k each
  float a1[8], a3[8];
  #pragma unroll
  for (int f=0;f<8;f++){ a1[f]=0.f; a3[f]=0.f; }
  const float* w1p = w1 + (size_t)e*DIM*HID + (size_t)(kc*512)*HID + j;
  const float* w3p = w3 + (size_t)e*DIM*HID + (size_t)(kc*512)*HID + j;
  #pragma unroll 4
  for (int k=kp*64; k<kp*64+64; ++k){
    float w1v = w1p[(size_t)k*HID];
    float w3v = w3p[(size_t)k*HID];
    #pragma unroll
    for (int f=0;f<8;f++){
      float xv = xs[f*512 + k];
      a1[f] += xv*w1v;
      a3[f] += xv*w3v;
    }
  }
  #pragma unroll
  for (int f=0;f<8;f++){ red[kp][t&31][f] = a1[f]; red[kp][t&31][8+f] = a3[f]; }
  __syncthreads();
  if (kp==0){
    #pragma unroll
    for (int f=0;f<8;f++){
      float s1=0.f, s3=0.f;
      #pragma unroll
      for (int q=0;q<8;q++){ s1 += red[q][t][f]; s3 += red[q][t][8+f]; }
      P1[((size_t)(kc*64) + f*8 + e)*HID + j] = s1;
      P3[((size_t)(kc*64) + f*8 + e)*HID + j] = s3;
    }
  }
}

// ---------------- scatter rows into (f, eid) buckets (cumsum in-register) ----------------
__global__ __launch_bounds__(256) void scat_k(const int* __restrict__ topk,
    const float* __restrict__ wts, const int* __restrict__ counts,
    int* __restrict__ bcount, float* __restrict__ bw)
{
  int i = blockIdx.x*256 + threadIdx.x;
  if (i >= NROW) return;
  int offv[NE]; int s=0;
  #pragma unroll
  for (int q=0;q<NE;q++){ s += counts[q]; offv[q]=s; }   // inclusive cumsum
  int f = topk[i];
  int e = 0;
  #pragma unroll
  for (int q=0;q<NE;q++) if (i >= offv[q]) e = q+1;      // searchsorted right
  float w = wts[i];
  int b = f*8 + e;
  int slot = atomicAdd(&bcount[b], 1);
  bw[(size_t)b*NROW + slot] = w;
}

// ---------------- partial silu-weighted sums: S[b][j] += sum_q w silu(w*a) ----------------
// grid 512 = b(64) x chunk(8); threads 256, 2 cols each
__global__ __launch_bounds__(256) void ssum_k(const float* __restrict__ P1,
    const int* __restrict__ bcount, const float* __restrict__ bw,
    float* __restrict__ S)
{
  int b = blockIdx.x >> 3;
  int c = blockIdx.x & 7;
  int t = threadIdx.x;
  int n = bcount[b];
  float a0 = P1[(size_t)b*HID + t]       + P1[(size_t)(64+b)*HID + t];
  float a1 = P1[(size_t)b*HID + t + 256] + P1[(size_t)(64+b)*HID + t + 256];
  float s0 = 0.f, s1 = 0.f;
  const float* wp = bw + (size_t)b*NROW;
  for (int q=c; q<n; q+=8){
    float w = wp[q];
    float z0 = w*a0, z1 = w*a1;
    s0 += w * z0 / (1.f + expf(-z0));   // w * silu(w*a)
    s1 += w * z1 / (1.f + expf(-z1));
  }
  if (n > c){
    atomicAdd(&S[(size_t)b*HID + t],       s0);
    atomicAdd(&S[(size_t)b*HID + t + 256], s1);
  }
}

// ---------------- routed out: out[r][d] += sum_e (P3[r,e]*S[r,e]) @ w2[e][:,d] ---------
// grid 256 = e(8) x dc(16) x jh(2); threads 256 = 64 d x 4 jp (64 j each)
__global__ __launch_bounds__(256) void rout_k(const float* __restrict__ P3,
    const float* __restrict__ S, const float* __restrict__ w2,
    float* __restrict__ out)
{
  __shared__ float Hs[8*256];          // 8KB
  __shared__ float red[4][64][8];      // 8KB
  int e  = blockIdx.x >> 5;
  int dc = (blockIdx.x >> 1) & 15;
  int jh = blockIdx.x & 1;
  int t  = threadIdx.x;
  for (int q=t; q<2048; q+=256){
    int r = q >> 8; int jl = q & 255;
    size_t idx = (size_t)(r*8 + e)*HID + jh*256 + jl;
    Hs[q] = (P3[idx] + P3[(size_t)64*HID + idx]) * S[idx];
  }
  __syncthreads();
  int d  = dc*64 + (t & 63);
  int jp = t >> 6;                      // 0..3, 64 j each
  float acc[8];
  #pragma unroll
  for (int r=0;r<8;r++) acc[r]=0.f;
  const float* w2p = w2 + (size_t)e*HID*DIM + (size_t)(jh*256)*DIM + d;
  #pragma unroll 4
  for (int jl=jp*64; jl<jp*64+64; ++jl){
    float wv = w2p[(size_t)jl*DIM];
    #pragma unroll
    for (int r=0;r<8;r++) acc[r] += Hs[r*256 + jl]*wv;
  }
  #pragma unroll
  for (int r=0;r<8;r++) red[jp][t&63][r] = acc[r];
  __syncthreads();
  if (jp==0){
    #pragma unroll
    for (int r=0;r<8;r++){
      float v = red[0][t][r] + red[1][t][r] + red[2][t][r] + red[3][t][r];
      atomicAdd(&out[(size_t)r*DIM + d], v);
    }
  }
}

extern "C" void kernel_launch(void* const* d_in, const int* in_sizes, int n_in,
                              void* d_out, int out_size, void* d_ws, size_t ws_size,
                              hipStream_t stream)
{
  const float* x    = (const float*)d_in[0];
  const float* wg   = (const float*)d_in[1];
  const float* w1   = (const float*)d_in[2];
  const float* w2   = (const float*)d_in[3];   // NOTE: w2 before w3 in dict order
  const float* w3   = (const float*)d_in[4];
  const float* sw1  = (const float*)d_in[5];
  const float* sw2  = (const float*)d_in[6];   // sw2 before sw3
  const float* sw3  = (const float*)d_in[7];
  const float* bias = (const float*)d_in[8];
  float* out = (float*)d_out;

  char* wsp = (char*)d_ws;
  size_t off = 0;
  auto alloc = [&](size_t bytes)->char*{
    char* p = wsp + off; off += (bytes + 255) & ~(size_t)255; return p;
  };
  unsigned short* xb   = (unsigned short*)alloc((size_t)NTOK*DIM*2);
  unsigned short* s1b  = (unsigned short*)alloc((size_t)SHID*DIM*2);
  unsigned short* s3b  = (unsigned short*)alloc((size_t)SHID*DIM*2);
  unsigned short* s2b  = (unsigned short*)alloc((size_t)DIM*SHID*2);
  unsigned short* hb   = (unsigned short*)alloc((size_t)NTOK*SHID*2);
  float*          lgt  = (float*)alloc((size_t)NTOK*NE*4);
  int*            topk = (int*)alloc(NROW*4);
  float*          wtsb = (float*)alloc(NROW*4);
  int*            cnts = (int*)alloc(64);
  int*            bcnt = (int*)alloc(256);
  float*          P1   = (float*)alloc(2*64*HID*4);
  float*          P3   = (float*)alloc(2*64*HID*4);
  float*          Sbuf = (float*)alloc(64*HID*4);
  float*          bwb  = (float*)alloc((size_t)64*NROW*4);
  (void)ws_size; (void)in_sizes; (void)n_in; (void)out_size;

  const int NW = (SHID*DIM)/4;
  cvtall_k<<<(3*NW)/256, 256, 0, stream>>>(sw1, sw3, sw2, s1b, s3b, s2b);
  logits_k<<<NTOK/4, 256, 0, stream>>>(x, wg, lgt, xb, cnts, bcnt);
  topk_k<<<NTOK/256, 256, 0, stream>>>(lgt, bias, topk, wtsb, cnts, Sbuf);
  scat_k<<<NROW/256, 256, 0, stream>>>(topk, wtsb, cnts, bcnt, bwb);
  pgemv_k<<<256, 256, 0, stream>>>(x, w1, w3, P1, P3);
  ssum_k<<<512, 256, 0, stream>>>(P1, bcnt, bwb, Sbuf);

  // fused shared-expert FFN: hb = silu(x@sw1^T) * (x@sw3^T), then out = hb@sw2^T
  gemm_k<1><<<(NTOK/128)*(SHID/128), 512, 0, stream>>>(xb, s1b, s3b, hb, nullptr, NTOK, SHID, DIM);
  gemm_k<0><<<(NTOK/128)*(DIM/128),  512, 0, stream>>>(hb, s2b, nullptr, nullptr, out, NTOK, DIM, SHID);

  rout_k<<<256, 256, 0, stream>>>(P3, Sbuf, w2, out);
}